// Round 1
// baseline (830.923 us; speedup 1.0000x reference)
//
#include <hip/hip_runtime.h>
#include <hip/hip_bf16.h>
#include <stdint.h>
#include <stddef.h>

typedef _Float16 half2_t __attribute__((ext_vector_type(2)));

__device__ __forceinline__ float fdot2(half2_t a, half2_t b, float c) {
#if __has_builtin(__builtin_amdgcn_fdot2)
  return __builtin_amdgcn_fdot2(a, b, c, false);
#else
  return c + (float)a.x * (float)b.x + (float)a.y * (float)b.y;
#endif
}

// ---------------- param_net stage 1: partial h = X @ W1 (K-split) ----------
// grid (32 ksplit, 16 bsplit), block 128 (j). Each thread holds a 128-deep
// W1 column chunk in registers; X row chunks are wave-uniform -> s_load.
__global__ __launch_bounds__(128) void k_paramnet1(
    const float* __restrict__ X, const float* __restrict__ W1,
    float* __restrict__ hpart) {
  const int j = threadIdx.x;
  const int ks = blockIdx.x;
  const int b0 = blockIdx.y * 32;

  float w1r[128];
#pragma unroll
  for (int k = 0; k < 128; ++k)
    w1r[k] = W1[(size_t)(ks * 128 + k) * 128 + j];

  for (int bb = 0; bb < 32; ++bb) {
    const float* xr = X + (size_t)(b0 + bb) * 4096 + ks * 128;
    float a0 = 0.f, a1 = 0.f, a2 = 0.f, a3 = 0.f;
#pragma unroll
    for (int k = 0; k < 128; k += 4) {
      a0 = fmaf(w1r[k + 0], xr[k + 0], a0);
      a1 = fmaf(w1r[k + 1], xr[k + 1], a1);
      a2 = fmaf(w1r[k + 2], xr[k + 2], a2);
      a3 = fmaf(w1r[k + 3], xr[k + 3], a3);
    }
    hpart[((size_t)ks * 512 + (b0 + bb)) * 128 + j] = (a0 + a1) + (a2 + a3);
  }
}

// ---------------- param_net stage 2: reduce partials + bias + relu ---------
__global__ __launch_bounds__(256) void k_paramnet2(
    const float* __restrict__ hpart, const float* __restrict__ b1,
    float* __restrict__ h) {
  const int idx = blockIdx.x * 256 + threadIdx.x;  // b*128+j, 65536 total
  float s = b1[idx & 127];
#pragma unroll
  for (int ks = 0; ks < 32; ++ks) s += hpart[(size_t)ks * 65536 + idx];
  h[idx] = fmaxf(s, 0.f);
}

// ---------------- params = h @ W2 + b2 -> sigmoids -> SEIR init state ------
// grid 512 (b), block 256 (t). Thread t computes beta/sigma/gamma/e0 slots.
__global__ __launch_bounds__(256) void k_params_state(
    const float* __restrict__ h, const float* __restrict__ W2,
    const float* __restrict__ b2, const float* __restrict__ X,
    float* __restrict__ betaW, float* __restrict__ sigmaW,
    float* __restrict__ gammaW, float* __restrict__ S0W,
    float* __restrict__ E0W, float* __restrict__ I0W) {
  const int b = blockIdx.x;
  const int t = threadIdx.x;
  const float* hr = h + b * 128;
  float a0 = b2[t], a1 = b2[256 + t], a2 = b2[512 + t], a3 = b2[768 + t];
#pragma unroll 4
  for (int k = 0; k < 128; ++k) {
    const float hv = hr[k];
    const float* wr = W2 + (size_t)k * 1024;
    a0 = fmaf(hv, wr[t], a0);
    a1 = fmaf(hv, wr[256 + t], a1);
    a2 = fmaf(hv, wr[512 + t], a2);
    a3 = fmaf(hv, wr[768 + t], a3);
  }
  const float beta = 3.f / (1.f + __expf(-a0));
  const float sig  = 1.f / (1.f + __expf(-a1));
  const float gam  = 1.f / (1.f + __expf(-a2));
  const float e0r  = 5.f / (1.f + __expf(-a3));
  const int base = b * 256 + t;
  const float I0 = fmaxf(X[(size_t)b * 4096 + 15 * 256 + t], 1e-6f);
  const float E0 = I0 * e0r;
  const float S0 = fmaxf(1.f - E0 - I0, 0.01f);
  betaW[base] = beta; sigmaW[base] = sig; gammaW[base] = gam;
  S0W[base] = S0; E0W[base] = E0; I0W[base] = I0;
}

// ---------------- mobility stage 1: hm = relu(cnn @ M1 + mb1) as f16 -------
__global__ __launch_bounds__(128) void k_mobility1(
    const float* __restrict__ cnn, const float* __restrict__ M1,
    const float* __restrict__ mb1, _Float16* __restrict__ hmf) {
  const int b = blockIdx.x, j = threadIdx.x;
  const float* cr = cnn + b * 64;
  float a = mb1[j];
#pragma unroll
  for (int k = 0; k < 64; ++k) a = fmaf(cr[k], M1[k * 128 + j], a);
  hmf[b * 128 + j] = (_Float16)fmaxf(a, 0.f);
}

// ---------------- mobility stage 2: G = hm@M2 + mb2, row-softmax -> Pi f16 -
// grid (256 n, 4 bt), block 512 = (m 0..255) x (bq 0..1). M2 column held in
// 64 half2 regs per thread; hm rows wave-uniform (s_load). G tile lives in
// the same 64KB LDS as the staged M2 tile (dead after reg extraction).
__global__ __launch_bounds__(512, 4) void k_mobility2(
    const _Float16* __restrict__ hmf, const float* __restrict__ M2,
    const float* __restrict__ mb2, _Float16* __restrict__ PiF,
    float* __restrict__ pimpart) {
  const int n = blockIdx.x;
  const int bt = blockIdx.y;
  const int tid = threadIdx.x;
  const int m = tid & 255;
  const int bq = __builtin_amdgcn_readfirstlane(tid >> 8);

  __shared__ _Float16 sm[32768];  // 64 KB: phase0/1 = M2 tile (k-pair packed), phase2+ = G

  // phase 0: stage M2 (128k x 256m) f32 -> f16, k-pairs interleaved per m
  {
    const float* M2n = M2 + (size_t)n * 256;
    for (int it = 0; it < 64; ++it) {
      const int idx = it * 512 + tid;
      const int k = idx >> 8, mm = idx & 255;
      sm[(k >> 1) * 512 + mm * 2 + (k & 1)] = (_Float16)M2n[(size_t)k * 65536 + mm];
    }
  }
  __syncthreads();

  // phase 1: extract my column into registers
  half2_t m2r[64];
  {
    const half2_t* mp = (const half2_t*)sm;
#pragma unroll
    for (int k2 = 0; k2 < 64; ++k2) m2r[k2] = mp[k2 * 256 + m];
  }
  __syncthreads();

  // phase 2: G for my 64 b's, write f16 into sm[b][m] (stride 256)
  const float mbv = mb2[n * 256 + m];
  const uint4* hm4base = (const uint4*)(hmf + (size_t)(bt * 128 + bq * 64) * 128);
  for (int bo = 0; bo < 8; ++bo) {
    float acc[8];
#pragma unroll
    for (int bi = 0; bi < 8; ++bi) acc[bi] = mbv;
#pragma unroll
    for (int bi = 0; bi < 8; ++bi) {
      const uint4* hr = hm4base + (bo * 8 + bi) * 16;
#pragma unroll
      for (int kc = 0; kc < 16; ++kc) {
        const uint4 hv = hr[kc];
        acc[bi] = fdot2(m2r[kc * 4 + 0], __builtin_bit_cast(half2_t, hv.x), acc[bi]);
        acc[bi] = fdot2(m2r[kc * 4 + 1], __builtin_bit_cast(half2_t, hv.y), acc[bi]);
        acc[bi] = fdot2(m2r[kc * 4 + 2], __builtin_bit_cast(half2_t, hv.z), acc[bi]);
        acc[bi] = fdot2(m2r[kc * 4 + 3], __builtin_bit_cast(half2_t, hv.w), acc[bi]);
      }
    }
#pragma unroll
    for (int bi = 0; bi < 8; ++bi)
      sm[(bq * 64 + bo * 8 + bi) * 256 + m] = (_Float16)acc[bi];
  }
  __syncthreads();

  // phase 3: softmax over each row (4 lanes per row); lane-rotated index
  // breaks the 64-way bank aliasing of the 512B row stride.
  {
    const int rb = tid >> 2, mq = tid & 3;
    const int rot = 2 * (tid & 31);
    _Float16* Gr = sm + rb * 256 + mq * 64;
    float g[64];
#pragma unroll
    for (int i = 0; i < 64; ++i) g[i] = (float)Gr[(i + rot) & 63];
    float mx = g[0];
#pragma unroll
    for (int i = 1; i < 64; ++i) mx = fmaxf(mx, g[i]);
    mx = fmaxf(mx, __shfl_xor(mx, 1, 4));
    mx = fmaxf(mx, __shfl_xor(mx, 2, 4));
    float s = 0.f;
#pragma unroll
    for (int i = 0; i < 64; ++i) { g[i] = __expf(g[i] - mx); s += g[i]; }
    s += __shfl_xor(s, 1, 4);
    s += __shfl_xor(s, 2, 4);
    const float r = 1.f / s;
    const int gb = bt * 128 + rb;
    _Float16* Pp = PiF + ((size_t)gb * 256 + n) * 256 + mq * 64;
#pragma unroll
    for (int i = 0; i < 64; ++i) {
      const _Float16 ph = (_Float16)(g[i] * r);
      const int off = (i + rot) & 63;
      Pp[off] = ph;   // global Pi[b][n][m]
      Gr[off] = ph;   // back into LDS for the mean pass
    }
  }
  __syncthreads();

  // phase 4: per-block partial of Pi.mean over b
  if (tid < 256) {
    float s = 0.f;
#pragma unroll 16
    for (int bb = 0; bb < 128; ++bb) s += (float)sm[bb * 256 + tid];
    pimpart[((size_t)bt * 256 + n) * 256 + tid] = s;
  }
}

// ---------------- means of beta/sigma/gamma and Pi ------------------------
__global__ __launch_bounds__(256) void k_finalize(
    const float* __restrict__ betaW, const float* __restrict__ sigmaW,
    const float* __restrict__ gammaW, const float* __restrict__ pimpart,
    float* __restrict__ out) {
  const int idx = blockIdx.x * 256 + threadIdx.x;  // 66304 total
  const float inv = 1.f / 512.f;
  if (idx < 768) {
    const float* src = (idx < 256) ? betaW : (idx < 512) ? sigmaW : gammaW;
    const int t = idx & 255;
    float s = 0.f;
    for (int bb = 0; bb < 512; ++bb) s += src[bb * 256 + t];
    out[3145728 + idx] = s * inv;
  } else {
    const int pm = idx - 768;
    const float s = pimpart[pm] + pimpart[65536 + pm] +
                    pimpart[131072 + pm] + pimpart[196608 + pm];
    out[3146496 + pm] = s * inv;
  }
}

// ---------------- SEIR RK4 simulation -------------------------------------
// grid 512 (b), block 256 (m). Thread m holds Pi[:,m] as 128 half2 in VGPRs;
// stage-I goes through a double-buffered 512B LDS vector; 1 barrier/stage.
__global__ __launch_bounds__(256, 2) void k_sim(
    const _Float16* __restrict__ PiF, const float* __restrict__ betaW,
    const float* __restrict__ sigmaW, const float* __restrict__ gammaW,
    const float* __restrict__ S0W, const float* __restrict__ E0W,
    const float* __restrict__ I0W, float* __restrict__ out) {
  const int b = blockIdx.x, m = threadIdx.x;
  __shared__ _Float16 Ib[2][256];

  half2_t pi[128];
  {
    const _Float16* P = PiF + (size_t)b * 65536 + m;
#pragma unroll
    for (int t = 0; t < 128; ++t) {
      const _Float16 lo = P[(2 * t) * 256];
      const _Float16 hi = P[(2 * t + 1) * 256];
      pi[t] = half2_t{lo, hi};
    }
  }
  const int base = b * 256 + m;
  const float bet = betaW[base], sig = sigmaW[base], gam = gammaW[base];
  float S = S0W[base], E = E0W[base], I = I0W[base];

  int p = 0;
  auto grads = [&](float Ss, float Es, float Is, float& dS, float& dE, float& dI) {
    Ib[p][m] = (_Float16)Is;
    __syncthreads();
    const half2_t* iv = (const half2_t*)Ib[p];
    float a0 = 0.f, a1 = 0.f, a2 = 0.f, a3 = 0.f;
#pragma unroll
    for (int t = 0; t < 128; t += 4) {
      a0 = fdot2(pi[t + 0], iv[t + 0], a0);
      a1 = fdot2(pi[t + 1], iv[t + 1], a1);
      a2 = fdot2(pi[t + 2], iv[t + 2], a2);
      a3 = fdot2(pi[t + 3], iv[t + 3], a3);
    }
    const float force = (a0 + a1) + (a2 + a3);
    p ^= 1;
    const float ninf = bet * Ss * force;
    const float sE = sig * Es;
    dS = -ninf;
    dE = ninf - sE;
    dI = sE - gam * Is;
  };

  float* outI = out + (size_t)b * (12 * 256) + m;
  float* outE = outI + 1572864;
  const float c6 = 0.25f / 6.f;

  for (int w = 0; w < 12; ++w) {
    for (int st = 0; st < 4; ++st) {
      float d1S, d1E, d1I, d2S, d2E, d2I, d3S, d3E, d3I, d4S, d4E, d4I;
      grads(S, E, I, d1S, d1E, d1I);
      grads(S + 0.125f * d1S, E + 0.125f * d1E, I + 0.125f * d1I, d2S, d2E, d2I);
      grads(S + 0.125f * d2S, E + 0.125f * d2E, I + 0.125f * d2I, d3S, d3E, d3I);
      grads(S + 0.25f * d3S, E + 0.25f * d3E, I + 0.25f * d3I, d4S, d4E, d4I);
      S = fminf(fmaxf(S + c6 * (d1S + 2.f * d2S + 2.f * d3S + d4S), 0.f), 1.f);
      E = fminf(fmaxf(E + c6 * (d1E + 2.f * d2E + 2.f * d3E + d4E), 0.f), 1.f);
      I = fminf(fmaxf(I + c6 * (d1I + 2.f * d2I + 2.f * d3I + d4I), 0.f), 1.f);
    }
    outI[w * 256] = I;
    outE[w * 256] = E;
  }
}

// ---------------- launch ---------------------------------------------------
extern "C" void kernel_launch(void* const* d_in, const int* in_sizes, int n_in,
                              void* d_out, int out_size, void* d_ws, size_t ws_size,
                              hipStream_t stream) {
  const float* x_hist = (const float*)d_in[0];
  const float* cnn    = (const float*)d_in[1];
  const float* W1     = (const float*)d_in[2];
  const float* b1     = (const float*)d_in[3];
  const float* W2     = (const float*)d_in[4];
  const float* b2     = (const float*)d_in[5];
  const float* M1     = (const float*)d_in[6];
  const float* mb1    = (const float*)d_in[7];
  const float* M2     = (const float*)d_in[8];
  const float* mb2    = (const float*)d_in[9];
  float* out = (float*)d_out;

  char* w = (char*)d_ws;
  float*    hpart   = (float*)(w + 0);          //  8,388,608 B
  float*    h       = (float*)(w + 8388608);    //    262,144
  _Float16* hmf     = (_Float16*)(w + 8650752); //    131,072
  float*    betaW   = (float*)(w + 8781824);    //    524,288
  float*    sigmaW  = (float*)(w + 9306112);
  float*    gammaW  = (float*)(w + 9830400);
  float*    S0W     = (float*)(w + 10354688);
  float*    E0W     = (float*)(w + 10878976);
  float*    I0W     = (float*)(w + 11403264);
  float*    pimpart = (float*)(w + 11927552);   //  1,048,576
  _Float16* PiF     = (_Float16*)(w + 12976128);// 67,108,864  (total ~80.1 MB)

  k_paramnet1<<<dim3(32, 16), 128, 0, stream>>>(x_hist, W1, hpart);
  k_paramnet2<<<256, 256, 0, stream>>>(hpart, b1, h);
  k_params_state<<<512, 256, 0, stream>>>(h, W2, b2, x_hist, betaW, sigmaW,
                                          gammaW, S0W, E0W, I0W);
  k_mobility1<<<512, 128, 0, stream>>>(cnn, M1, mb1, hmf);
  k_mobility2<<<dim3(256, 4), 512, 0, stream>>>(hmf, M2, mb2, PiF, pimpart);
  k_finalize<<<259, 256, 0, stream>>>(betaW, sigmaW, gammaW, pimpart, out);
  k_sim<<<512, 256, 0, stream>>>(PiF, betaW, sigmaW, gammaW, S0W, E0W, I0W, out);
}

// Round 2
// 759.157 us; speedup vs baseline: 1.0945x; 1.0945x over previous
//
#include <hip/hip_runtime.h>
#include <hip/hip_bf16.h>
#include <stdint.h>
#include <stddef.h>

typedef _Float16 half2_t __attribute__((ext_vector_type(2)));

__device__ __forceinline__ float fdot2(half2_t a, half2_t b, float c) {
#if __has_builtin(__builtin_amdgcn_fdot2)
  return __builtin_amdgcn_fdot2(a, b, c, false);
#else
  return c + (float)a.x * (float)b.x + (float)a.y * (float)b.y;
#endif
}

// ---------------- param_net stage 1: partial h = X @ W1 (K-split) ----------
__global__ __launch_bounds__(128) void k_paramnet1(
    const float* __restrict__ X, const float* __restrict__ W1,
    float* __restrict__ hpart) {
  const int j = threadIdx.x;
  const int ks = blockIdx.x;
  const int b0 = blockIdx.y * 32;

  float w1r[128];
#pragma unroll
  for (int k = 0; k < 128; ++k)
    w1r[k] = W1[(size_t)(ks * 128 + k) * 128 + j];

  for (int bb = 0; bb < 32; ++bb) {
    const float* xr = X + (size_t)(b0 + bb) * 4096 + ks * 128;
    float a0 = 0.f, a1 = 0.f, a2 = 0.f, a3 = 0.f;
#pragma unroll
    for (int k = 0; k < 128; k += 4) {
      a0 = fmaf(w1r[k + 0], xr[k + 0], a0);
      a1 = fmaf(w1r[k + 1], xr[k + 1], a1);
      a2 = fmaf(w1r[k + 2], xr[k + 2], a2);
      a3 = fmaf(w1r[k + 3], xr[k + 3], a3);
    }
    hpart[((size_t)ks * 512 + (b0 + bb)) * 128 + j] = (a0 + a1) + (a2 + a3);
  }
}

// ---------------- param_net stage 2: reduce partials + bias + relu ---------
__global__ __launch_bounds__(256) void k_paramnet2(
    const float* __restrict__ hpart, const float* __restrict__ b1,
    float* __restrict__ h) {
  const int idx = blockIdx.x * 256 + threadIdx.x;
  float s = b1[idx & 127];
#pragma unroll
  for (int ks = 0; ks < 32; ++ks) s += hpart[(size_t)ks * 65536 + idx];
  h[idx] = fmaxf(s, 0.f);
}

// ---------------- params = h @ W2 + b2 -> sigmoids -> SEIR init state ------
// 2 batch rows per block: W2 row loads amortized 2x.
__global__ __launch_bounds__(256) void k_params_state(
    const float* __restrict__ h, const float* __restrict__ W2,
    const float* __restrict__ b2, const float* __restrict__ X,
    float* __restrict__ betaW, float* __restrict__ sigmaW,
    float* __restrict__ gammaW, float* __restrict__ S0W,
    float* __restrict__ E0W, float* __restrict__ I0W) {
  const int b0 = blockIdx.x * 2;
  const int t = threadIdx.x;
  const float* h0 = h + (size_t)b0 * 128;
  const float* h1 = h0 + 128;
  float a00 = b2[t], a01 = b2[256 + t], a02 = b2[512 + t], a03 = b2[768 + t];
  float a10 = a00, a11 = a01, a12 = a02, a13 = a03;
#pragma unroll 2
  for (int k = 0; k < 128; ++k) {
    const float* wr = W2 + (size_t)k * 1024;
    const float w0 = wr[t], w1 = wr[256 + t], w2 = wr[512 + t], w3 = wr[768 + t];
    const float hv0 = h0[k], hv1 = h1[k];
    a00 = fmaf(hv0, w0, a00); a01 = fmaf(hv0, w1, a01);
    a02 = fmaf(hv0, w2, a02); a03 = fmaf(hv0, w3, a03);
    a10 = fmaf(hv1, w0, a10); a11 = fmaf(hv1, w1, a11);
    a12 = fmaf(hv1, w2, a12); a13 = fmaf(hv1, w3, a13);
  }
#pragma unroll
  for (int j = 0; j < 2; ++j) {
    const float p0 = j ? a10 : a00, p1 = j ? a11 : a01;
    const float p2 = j ? a12 : a02, p3 = j ? a13 : a03;
    const float beta = 3.f / (1.f + __expf(-p0));
    const float sig  = 1.f / (1.f + __expf(-p1));
    const float gam  = 1.f / (1.f + __expf(-p2));
    const float e0r  = 5.f / (1.f + __expf(-p3));
    const int base = (b0 + j) * 256 + t;
    const float I0 = fmaxf(X[(size_t)(b0 + j) * 4096 + 15 * 256 + t], 1e-6f);
    const float E0 = I0 * e0r;
    const float S0 = fmaxf(1.f - E0 - I0, 0.01f);
    betaW[base] = beta; sigmaW[base] = sig; gammaW[base] = gam;
    S0W[base] = S0; E0W[base] = E0; I0W[base] = I0;
  }
}

// ---------------- mobility stage 1: hm = relu(cnn @ M1 + mb1) as f16 -------
__global__ __launch_bounds__(128) void k_mobility1(
    const float* __restrict__ cnn, const float* __restrict__ M1,
    const float* __restrict__ mb1, _Float16* __restrict__ hmf) {
  const int b = blockIdx.x, j = threadIdx.x;
  const float* cr = cnn + b * 64;
  float a = mb1[j];
#pragma unroll
  for (int k = 0; k < 64; ++k) a = fmaf(cr[k], M1[k * 128 + j], a);
  hmf[b * 128 + j] = (_Float16)fmaxf(a, 0.f);
}

// ---------------- pre-pack M2 f32 -> f16 k-pair format ---------------------
// M2p[k2][nm] = half2{M2[2k2][nm], M2[2k2+1][nm]}
__global__ __launch_bounds__(256) void k_cvtM2(
    const float* __restrict__ M2, uint32_t* __restrict__ M2p) {
  const int i = blockIdx.x * 256 + threadIdx.x;  // 0..65535
  const int k2 = blockIdx.y;                     // 0..63
  half2_t hv;
  hv.x = (_Float16)M2[(size_t)(2 * k2) * 65536 + i];
  hv.y = (_Float16)M2[(size_t)(2 * k2 + 1) * 65536 + i];
  M2p[(size_t)k2 * 65536 + i] = __builtin_bit_cast(uint32_t, hv);
}

// ---------------- mobility stage 2: G = hm@M2 + mb2, row-softmax -> Pi f16 -
// launch_bounds(512,1): release the VGPR cap (the (512,4) bound forced a
// 64-VGPR allocation and ~800MB of scratch spill traffic in round 1).
__global__ __launch_bounds__(512, 1) void k_mobility2(
    const _Float16* __restrict__ hmf, const float* __restrict__ M2,
    const uint32_t* __restrict__ M2p, const int useM2p,
    const float* __restrict__ mb2, _Float16* __restrict__ PiF,
    float* __restrict__ pimpart) {
  const int n = blockIdx.x;
  const int bt = blockIdx.y;
  const int tid = threadIdx.x;
  const int m = tid & 255;
  const int bq = __builtin_amdgcn_readfirstlane(tid >> 8);

  __shared__ _Float16 sm[32768];  // 64 KB: phase0/1 = M2 tile (k-pair packed), phase2+ = G

  // phase 0: stage M2 tile as k-pair-packed f16 [k2][m-column of this n]
  if (useM2p) {
    uint32_t* sm32 = (uint32_t*)sm;
    const uint32_t* src = M2p + (size_t)n * 256;
    for (int it = 0; it < 32; ++it) {
      const int idx = it * 512 + tid;
      const int k2 = idx >> 8, mm = idx & 255;
      sm32[k2 * 256 + mm] = src[(size_t)k2 * 65536 + mm];
    }
  } else {
    const float* M2n = M2 + (size_t)n * 256;
    for (int it = 0; it < 64; ++it) {
      const int idx = it * 512 + tid;
      const int k = idx >> 8, mm = idx & 255;
      sm[(k >> 1) * 512 + mm * 2 + (k & 1)] = (_Float16)M2n[(size_t)k * 65536 + mm];
    }
  }
  __syncthreads();

  // phase 1: extract my column into registers
  half2_t m2r[64];
  {
    const half2_t* mp = (const half2_t*)sm;
#pragma unroll
    for (int k2 = 0; k2 < 64; ++k2) m2r[k2] = mp[k2 * 256 + m];
  }
  __syncthreads();

  // phase 2: G for my 64 b's, write f16 into sm[b][m]
  const float mbv = mb2[n * 256 + m];
  const uint4* hm4base = (const uint4*)(hmf + (size_t)(bt * 128 + bq * 64) * 128);
  for (int bo = 0; bo < 8; ++bo) {
    float acc[8];
#pragma unroll
    for (int bi = 0; bi < 8; ++bi) acc[bi] = mbv;
#pragma unroll
    for (int bi = 0; bi < 8; ++bi) {
      const uint4* hr = hm4base + (bo * 8 + bi) * 16;
#pragma unroll
      for (int kc = 0; kc < 16; ++kc) {
        const uint4 hv = hr[kc];
        acc[bi] = fdot2(m2r[kc * 4 + 0], __builtin_bit_cast(half2_t, hv.x), acc[bi]);
        acc[bi] = fdot2(m2r[kc * 4 + 1], __builtin_bit_cast(half2_t, hv.y), acc[bi]);
        acc[bi] = fdot2(m2r[kc * 4 + 2], __builtin_bit_cast(half2_t, hv.z), acc[bi]);
        acc[bi] = fdot2(m2r[kc * 4 + 3], __builtin_bit_cast(half2_t, hv.w), acc[bi]);
      }
    }
#pragma unroll
    for (int bi = 0; bi < 8; ++bi)
      sm[(bq * 64 + bo * 8 + bi) * 256 + m] = (_Float16)acc[bi];
  }
  __syncthreads();

  // phase 3: row softmax (4 lanes per row, lane-rotated LDS index)
  {
    const int rb = tid >> 2, mq = tid & 3;
    const int rot = 2 * (tid & 31);
    _Float16* Gr = sm + rb * 256 + mq * 64;
    float g[64];
#pragma unroll
    for (int i = 0; i < 64; ++i) g[i] = (float)Gr[(i + rot) & 63];
    float mx = g[0];
#pragma unroll
    for (int i = 1; i < 64; ++i) mx = fmaxf(mx, g[i]);
    mx = fmaxf(mx, __shfl_xor(mx, 1, 4));
    mx = fmaxf(mx, __shfl_xor(mx, 2, 4));
    float s = 0.f;
#pragma unroll
    for (int i = 0; i < 64; ++i) { g[i] = __expf(g[i] - mx); s += g[i]; }
    s += __shfl_xor(s, 1, 4);
    s += __shfl_xor(s, 2, 4);
    const float r = 1.f / s;
    const int gb = bt * 128 + rb;
    _Float16* Pp = PiF + ((size_t)gb * 256 + n) * 256 + mq * 64;
#pragma unroll
    for (int i = 0; i < 64; ++i) {
      const _Float16 ph = (_Float16)(g[i] * r);
      const int off = (i + rot) & 63;
      Pp[off] = ph;
      Gr[off] = ph;
    }
  }
  __syncthreads();

  // phase 4: per-block partial of Pi.mean over b
  if (tid < 256) {
    float s = 0.f;
#pragma unroll 16
    for (int bb = 0; bb < 128; ++bb) s += (float)sm[bb * 256 + tid];
    pimpart[((size_t)bt * 256 + n) * 256 + tid] = s;
  }
}

// ---------------- means of beta/sigma/gamma and Pi ------------------------
__global__ __launch_bounds__(256) void k_finalize(
    const float* __restrict__ betaW, const float* __restrict__ sigmaW,
    const float* __restrict__ gammaW, const float* __restrict__ pimpart,
    float* __restrict__ out) {
  const int idx = blockIdx.x * 256 + threadIdx.x;
  const float inv = 1.f / 512.f;
  if (idx < 768) {
    const float* src = (idx < 256) ? betaW : (idx < 512) ? sigmaW : gammaW;
    const int t = idx & 255;
    float s = 0.f;
    for (int bb = 0; bb < 512; ++bb) s += src[bb * 256 + t];
    out[3145728 + idx] = s * inv;
  } else {
    const int pm = idx - 768;
    const float s = pimpart[pm] + pimpart[65536 + pm] +
                    pimpart[131072 + pm] + pimpart[196608 + pm];
    out[3146496 + pm] = s * inv;
  }
}

// ---------------- SEIR RK4 simulation -------------------------------------
// DS-minimized: the whole 512B I-vector enters each wave with ONE
// ds_read_b128 (lane l holds 16B chunk l&31), then v_readlane (constant
// lane -> uniform SGPR) feeds v_dot2 with an SGPR operand. Replaces 32
// broadcast ds_read_b128 per wave per stage with 1.
__global__ __launch_bounds__(256, 2) void k_sim(
    const _Float16* __restrict__ PiF, const float* __restrict__ betaW,
    const float* __restrict__ sigmaW, const float* __restrict__ gammaW,
    const float* __restrict__ S0W, const float* __restrict__ E0W,
    const float* __restrict__ I0W, float* __restrict__ out) {
  const int b = blockIdx.x, m = threadIdx.x;
  __shared__ _Float16 Ib[2][256];

  half2_t pi[128];
  {
    const _Float16* P = PiF + (size_t)b * 65536 + m;
#pragma unroll
    for (int t = 0; t < 128; ++t) {
      const _Float16 lo = P[(2 * t) * 256];
      const _Float16 hi = P[(2 * t + 1) * 256];
      pi[t] = half2_t{lo, hi};
    }
  }
  const int base = b * 256 + m;
  const float bet = betaW[base], sig = sigmaW[base], gam = gammaW[base];
  float S = S0W[base], E = E0W[base], I = I0W[base];
  const int chunk = m & 31;

  int p = 0;
  auto grads = [&](float Ss, float Es, float Is, float& dS, float& dE, float& dI) {
    Ib[p][m] = (_Float16)Is;
    __syncthreads();
    const uint4 v = ((const uint4*)Ib[p])[chunk];
    p ^= 1;
    float a0 = 0.f, a1 = 0.f, a2 = 0.f, a3 = 0.f;
#pragma unroll
    for (int c = 0; c < 32; ++c) {
      const uint32_t s0 = __builtin_amdgcn_readlane(v.x, c);
      const uint32_t s1 = __builtin_amdgcn_readlane(v.y, c);
      const uint32_t s2 = __builtin_amdgcn_readlane(v.z, c);
      const uint32_t s3 = __builtin_amdgcn_readlane(v.w, c);
      a0 = fdot2(pi[c * 4 + 0], __builtin_bit_cast(half2_t, s0), a0);
      a1 = fdot2(pi[c * 4 + 1], __builtin_bit_cast(half2_t, s1), a1);
      a2 = fdot2(pi[c * 4 + 2], __builtin_bit_cast(half2_t, s2), a2);
      a3 = fdot2(pi[c * 4 + 3], __builtin_bit_cast(half2_t, s3), a3);
    }
    const float force = (a0 + a1) + (a2 + a3);
    const float ninf = bet * Ss * force;
    const float sE = sig * Es;
    dS = -ninf;
    dE = ninf - sE;
    dI = sE - gam * Is;
  };

  float* outI = out + (size_t)b * (12 * 256) + m;
  float* outE = outI + 1572864;
  const float c6 = 0.25f / 6.f;

  for (int w = 0; w < 12; ++w) {
    for (int st = 0; st < 4; ++st) {
      float d1S, d1E, d1I, d2S, d2E, d2I, d3S, d3E, d3I, d4S, d4E, d4I;
      grads(S, E, I, d1S, d1E, d1I);
      grads(S + 0.125f * d1S, E + 0.125f * d1E, I + 0.125f * d1I, d2S, d2E, d2I);
      grads(S + 0.125f * d2S, E + 0.125f * d2E, I + 0.125f * d2I, d3S, d3E, d3I);
      grads(S + 0.25f * d3S, E + 0.25f * d3E, I + 0.25f * d3I, d4S, d4E, d4I);
      S = fminf(fmaxf(S + c6 * (d1S + 2.f * d2S + 2.f * d3S + d4S), 0.f), 1.f);
      E = fminf(fmaxf(E + c6 * (d1E + 2.f * d2E + 2.f * d3E + d4E), 0.f), 1.f);
      I = fminf(fmaxf(I + c6 * (d1I + 2.f * d2I + 2.f * d3I + d4I), 0.f), 1.f);
    }
    outI[w * 256] = I;
    outE[w * 256] = E;
  }
}

// ---------------- launch ---------------------------------------------------
extern "C" void kernel_launch(void* const* d_in, const int* in_sizes, int n_in,
                              void* d_out, int out_size, void* d_ws, size_t ws_size,
                              hipStream_t stream) {
  const float* x_hist = (const float*)d_in[0];
  const float* cnn    = (const float*)d_in[1];
  const float* W1     = (const float*)d_in[2];
  const float* b1     = (const float*)d_in[3];
  const float* W2     = (const float*)d_in[4];
  const float* b2     = (const float*)d_in[5];
  const float* M1     = (const float*)d_in[6];
  const float* mb1    = (const float*)d_in[7];
  const float* M2     = (const float*)d_in[8];
  const float* mb2    = (const float*)d_in[9];
  float* out = (float*)d_out;

  // Region A [0, 16.7MB): hpart+h (dead after k_params_state) then reused by
  // M2p (written by k_cvtM2, read by k_mobility2). Fallback if ws too small.
  const int useM2p = (ws_size >= 88300000u) ? 1 : 0;
  char* w = (char*)d_ws;
  float*    hpart = (float*)(w + 0);
  float*    h     = (float*)(w + 8388608);
  uint32_t* M2p   = (uint32_t*)(w + 0);
  const size_t base = useM2p ? 16777216u : 8650752u;
  _Float16* hmf     = (_Float16*)(w + base);
  float*    betaW   = (float*)(w + base + 131072);
  float*    sigmaW  = (float*)(w + base + 131072 + 524288);
  float*    gammaW  = (float*)(w + base + 131072 + 2 * 524288);
  float*    S0W     = (float*)(w + base + 131072 + 3 * 524288);
  float*    E0W     = (float*)(w + base + 131072 + 4 * 524288);
  float*    I0W     = (float*)(w + base + 131072 + 5 * 524288);
  float*    pimpart = (float*)(w + base + 131072 + 6 * 524288);
  _Float16* PiF     = (_Float16*)(w + base + 131072 + 6 * 524288 + 1048576);

  k_paramnet1<<<dim3(32, 16), 128, 0, stream>>>(x_hist, W1, hpart);
  k_paramnet2<<<256, 256, 0, stream>>>(hpart, b1, h);
  k_params_state<<<256, 256, 0, stream>>>(h, W2, b2, x_hist, betaW, sigmaW,
                                          gammaW, S0W, E0W, I0W);
  k_mobility1<<<512, 128, 0, stream>>>(cnn, M1, mb1, hmf);
  if (useM2p)
    k_cvtM2<<<dim3(256, 64), 256, 0, stream>>>(M2, M2p);
  k_mobility2<<<dim3(256, 4), 512, 0, stream>>>(hmf, M2, M2p, useM2p, mb2,
                                                PiF, pimpart);
  k_finalize<<<259, 256, 0, stream>>>(betaW, sigmaW, gammaW, pimpart, out);
  k_sim<<<512, 256, 0, stream>>>(PiF, betaW, sigmaW, gammaW, S0W, E0W, I0W, out);
}

// Round 3
// 677.086 us; speedup vs baseline: 1.2272x; 1.1212x over previous
//
#include <hip/hip_runtime.h>
#include <hip/hip_bf16.h>
#include <stdint.h>
#include <stddef.h>

typedef _Float16 half2_t __attribute__((ext_vector_type(2)));
typedef _Float16 f16x8 __attribute__((ext_vector_type(8)));
typedef float f32x4 __attribute__((ext_vector_type(4)));

__device__ __forceinline__ float fdot2(half2_t a, half2_t b, float c) {
#if __has_builtin(__builtin_amdgcn_fdot2)
  return __builtin_amdgcn_fdot2(a, b, c, false);
#else
  return c + (float)a.x * (float)b.x + (float)a.y * (float)b.y;
#endif
}

// ---------------- param_net stage 1: partial h = X @ W1 (K-split) ----------
__global__ __launch_bounds__(128) void k_paramnet1(
    const float* __restrict__ X, const float* __restrict__ W1,
    float* __restrict__ hpart) {
  const int j = threadIdx.x;
  const int ks = blockIdx.x;
  const int b0 = blockIdx.y * 32;

  float w1r[128];
#pragma unroll
  for (int k = 0; k < 128; ++k)
    w1r[k] = W1[(size_t)(ks * 128 + k) * 128 + j];

  for (int bb = 0; bb < 32; ++bb) {
    const float* xr = X + (size_t)(b0 + bb) * 4096 + ks * 128;
    float a0 = 0.f, a1 = 0.f, a2 = 0.f, a3 = 0.f;
#pragma unroll
    for (int k = 0; k < 128; k += 4) {
      a0 = fmaf(w1r[k + 0], xr[k + 0], a0);
      a1 = fmaf(w1r[k + 1], xr[k + 1], a1);
      a2 = fmaf(w1r[k + 2], xr[k + 2], a2);
      a3 = fmaf(w1r[k + 3], xr[k + 3], a3);
    }
    hpart[((size_t)ks * 512 + (b0 + bb)) * 128 + j] = (a0 + a1) + (a2 + a3);
  }
}

// ---------------- param_net stage 2: reduce partials + bias + relu ---------
__global__ __launch_bounds__(256) void k_paramnet2(
    const float* __restrict__ hpart, const float* __restrict__ b1,
    float* __restrict__ h) {
  const int idx = blockIdx.x * 256 + threadIdx.x;
  float s = b1[idx & 127];
#pragma unroll
  for (int ks = 0; ks < 32; ++ks) s += hpart[(size_t)ks * 65536 + idx];
  h[idx] = fmaxf(s, 0.f);
}

// ---------------- params = h @ W2 + b2 -> sigmoids -> SEIR init state ------
__global__ __launch_bounds__(256) void k_params_state(
    const float* __restrict__ h, const float* __restrict__ W2,
    const float* __restrict__ b2, const float* __restrict__ X,
    float* __restrict__ betaW, float* __restrict__ sigmaW,
    float* __restrict__ gammaW, float* __restrict__ S0W,
    float* __restrict__ E0W, float* __restrict__ I0W) {
  const int b0 = blockIdx.x * 2;
  const int t = threadIdx.x;
  const float* h0 = h + (size_t)b0 * 128;
  const float* h1 = h0 + 128;
  float a00 = b2[t], a01 = b2[256 + t], a02 = b2[512 + t], a03 = b2[768 + t];
  float a10 = a00, a11 = a01, a12 = a02, a13 = a03;
#pragma unroll 2
  for (int k = 0; k < 128; ++k) {
    const float* wr = W2 + (size_t)k * 1024;
    const float w0 = wr[t], w1 = wr[256 + t], w2 = wr[512 + t], w3 = wr[768 + t];
    const float hv0 = h0[k], hv1 = h1[k];
    a00 = fmaf(hv0, w0, a00); a01 = fmaf(hv0, w1, a01);
    a02 = fmaf(hv0, w2, a02); a03 = fmaf(hv0, w3, a03);
    a10 = fmaf(hv1, w0, a10); a11 = fmaf(hv1, w1, a11);
    a12 = fmaf(hv1, w2, a12); a13 = fmaf(hv1, w3, a13);
  }
#pragma unroll
  for (int j = 0; j < 2; ++j) {
    const float p0 = j ? a10 : a00, p1 = j ? a11 : a01;
    const float p2 = j ? a12 : a02, p3 = j ? a13 : a03;
    const float beta = 3.f / (1.f + __expf(-p0));
    const float sig  = 1.f / (1.f + __expf(-p1));
    const float gam  = 1.f / (1.f + __expf(-p2));
    const float e0r  = 5.f / (1.f + __expf(-p3));
    const int base = (b0 + j) * 256 + t;
    const float I0 = fmaxf(X[(size_t)(b0 + j) * 4096 + 15 * 256 + t], 1e-6f);
    const float E0 = I0 * e0r;
    const float S0 = fmaxf(1.f - E0 - I0, 0.01f);
    betaW[base] = beta; sigmaW[base] = sig; gammaW[base] = gam;
    S0W[base] = S0; E0W[base] = E0; I0W[base] = I0;
  }
}

// ---------------- mobility stage 1: hm = relu(cnn @ M1 + mb1) as f16 -------
__global__ __launch_bounds__(128) void k_mobility1(
    const float* __restrict__ cnn, const float* __restrict__ M1,
    const float* __restrict__ mb1, _Float16* __restrict__ hmf) {
  const int b = blockIdx.x, j = threadIdx.x;
  const float* cr = cnn + b * 64;
  float a = mb1[j];
#pragma unroll
  for (int k = 0; k < 64; ++k) a = fmaf(cr[k], M1[k * 128 + j], a);
  hmf[b * 128 + j] = (_Float16)fmaxf(a, 0.f);
}

// ---------------- transpose M2 -> M2T[n][m][k] f16 -------------------------
// grid 256 (n), block 256 (m): thread m gathers its 128-deep k-column
// (coalesced across lanes per k), writes 256B contiguous.
__global__ __launch_bounds__(256) void k_cvtM2(
    const float* __restrict__ M2, _Float16* __restrict__ M2T) {
  const int n = blockIdx.x, m = threadIdx.x;
  half2_t row[64];
  const float* src = M2 + (size_t)n * 256 + m;
#pragma unroll 8
  for (int k2 = 0; k2 < 64; ++k2) {
    const float lo = src[(size_t)(2 * k2) * 65536];
    const float hi = src[(size_t)(2 * k2 + 1) * 65536];
    row[k2] = half2_t{(_Float16)lo, (_Float16)hi};
  }
  uint4* dst = (uint4*)(M2T + ((size_t)n * 256 + m) * 128);
  const uint4* s4 = (const uint4*)row;
#pragma unroll
  for (int i = 0; i < 16; ++i) dst[i] = s4[i];
}

// ---------------- mobility stage 2: MFMA GEMM + in-register softmax --------
// grid 256 (n), block 512 = 8 waves. Wave w: btile-pairs {4w,4w+1},{4w+2,4w+3}
// (btile = 16 b's). A = hm (b x k), B = M2T[n] (m x k, k-contig), both direct
// from global (L2-resident). C-layout: row b = q*4+reg, col m = nb*16+c.
// Softmax over m: in-lane across 16 nb-frags + shfl_xor over the 16 c-lanes.
// Output staged in a per-wave LDS slot, stored as coalesced dwordx4 rows.
__global__ __launch_bounds__(512, 2) void k_mobility2(
    const _Float16* __restrict__ hmf, const _Float16* __restrict__ M2T,
    const float* __restrict__ mb2, _Float16* __restrict__ PiF,
    float* __restrict__ pimpart) {
  const int n = blockIdx.x;
  const int tid = threadIdx.x;
  const int wave = tid >> 6;
  const int lane = tid & 63;
  const int q = lane >> 4;
  const int c = lane & 15;

  __shared__ _Float16 sm[8][16 * 256];  // 64 KB, wave-private slots

  const _Float16* Bbase = M2T + (size_t)n * 32768 + (size_t)c * 128 + q * 8;
  const float* mbp = mb2 + n * 256 + c;

  for (int pass = 0; pass < 2; ++pass) {
    const int bt0 = wave * 4 + pass * 2;
    f32x4 C0[16], C1[16];
#pragma unroll
    for (int nb = 0; nb < 16; ++nb) {
      const float mbv = mbp[nb * 16];
      C0[nb] = f32x4{mbv, mbv, mbv, mbv};
      C1[nb] = C0[nb];
    }
    const _Float16* A0 = hmf + (size_t)(bt0 * 16 + c) * 128 + q * 8;
    const _Float16* A1 = A0 + 16 * 128;
#pragma unroll
    for (int ks = 0; ks < 4; ++ks) {
      const f16x8 Af0 = *(const f16x8*)(A0 + ks * 32);
      const f16x8 Af1 = *(const f16x8*)(A1 + ks * 32);
#pragma unroll
      for (int nb = 0; nb < 16; ++nb) {
        const f16x8 Bf = *(const f16x8*)(Bbase + nb * 2048 + ks * 32);
        C0[nb] = __builtin_amdgcn_mfma_f32_16x16x32_f16(Af0, Bf, C0[nb], 0, 0, 0);
        C1[nb] = __builtin_amdgcn_mfma_f32_16x16x32_f16(Af1, Bf, C1[nb], 0, 0, 0);
      }
    }

    float colsum[16];
#pragma unroll
    for (int nb = 0; nb < 16; ++nb) colsum[nb] = 0.f;

#pragma unroll
    for (int half = 0; half < 2; ++half) {
      f32x4* C = half ? C1 : C0;
      const int bt = bt0 + half;
      // row-wise max over 256 cols (per reg r = one b-row)
      float mx[4], sum[4];
#pragma unroll
      for (int r = 0; r < 4; ++r) mx[r] = C[0][r];
#pragma unroll
      for (int nb = 1; nb < 16; ++nb)
#pragma unroll
        for (int r = 0; r < 4; ++r) mx[r] = fmaxf(mx[r], C[nb][r]);
#pragma unroll
      for (int r = 0; r < 4; ++r) {
        mx[r] = fmaxf(mx[r], __shfl_xor(mx[r], 1, 16));
        mx[r] = fmaxf(mx[r], __shfl_xor(mx[r], 2, 16));
        mx[r] = fmaxf(mx[r], __shfl_xor(mx[r], 4, 16));
        mx[r] = fmaxf(mx[r], __shfl_xor(mx[r], 8, 16));
        sum[r] = 0.f;
      }
#pragma unroll
      for (int nb = 0; nb < 16; ++nb)
#pragma unroll
        for (int r = 0; r < 4; ++r) {
          const float e = __expf(C[nb][r] - mx[r]);
          C[nb][r] = e;
          sum[r] += e;
        }
#pragma unroll
      for (int r = 0; r < 4; ++r) {
        sum[r] += __shfl_xor(sum[r], 1, 16);
        sum[r] += __shfl_xor(sum[r], 2, 16);
        sum[r] += __shfl_xor(sum[r], 4, 16);
        sum[r] += __shfl_xor(sum[r], 8, 16);
        sum[r] = 1.f / sum[r];
      }
      // normalize, accumulate column sums, stage to LDS slot
      _Float16* slot = sm[wave];
#pragma unroll
      for (int nb = 0; nb < 16; ++nb) {
#pragma unroll
        for (int r = 0; r < 4; ++r) {
          const float v = C[nb][r] * sum[r];
          colsum[nb] += v;
          slot[(q * 4 + r) * 256 + nb * 16 + c] = (_Float16)v;
        }
      }
      // coalesced copy: 16 rows x 512B, 2 rows per inst
      const int l2 = lane & 31, rh = lane >> 5;
      _Float16* Pg = PiF + ((size_t)(bt * 16) * 256 + n) * 256;
#pragma unroll
      for (int i = 0; i < 8; ++i) {
        const int row = i * 2 + rh;
        const uint4 v = *(const uint4*)(slot + row * 256 + l2 * 8);
        *(uint4*)(Pg + (size_t)row * 65536 + l2 * 8) = v;
      }
    }
    // Pi-mean partials: reduce colsum over q, atomically add (lanes 0..15)
#pragma unroll
    for (int nb = 0; nb < 16; ++nb) {
      colsum[nb] += __shfl_xor(colsum[nb], 16);
      colsum[nb] += __shfl_xor(colsum[nb], 32);
    }
    if (lane < 16) {
      float* pp = pimpart + n * 256 + lane;
#pragma unroll
      for (int nb = 0; nb < 16; ++nb) atomicAdd(pp + nb * 16, colsum[nb]);
    }
  }
}

// ---------------- means of beta/sigma/gamma and Pi ------------------------
__global__ __launch_bounds__(256) void k_finalize(
    const float* __restrict__ betaW, const float* __restrict__ sigmaW,
    const float* __restrict__ gammaW, const float* __restrict__ pimpart,
    float* __restrict__ out) {
  const int idx = blockIdx.x * 256 + threadIdx.x;
  const float inv = 1.f / 512.f;
  if (idx < 768) {
    const float* src = (idx < 256) ? betaW : (idx < 512) ? sigmaW : gammaW;
    const int t = idx & 255;
    float s = 0.f;
    for (int bb = 0; bb < 512; ++bb) s += src[bb * 256 + t];
    out[3145728 + idx] = s * inv;
  } else {
    const int pm = idx - 768;
    out[3146496 + pm] = pimpart[pm] * inv;
  }
}

// ---------------- SEIR RK4 simulation -------------------------------------
// Thread m holds column Pi[:,m] as 128 half2 in VGPRs, built at startup via
// LDS-tiled transpose (coalesced global dwordx4 + conflict-free column
// gather). Inner loop: broadcast ds_read + v_dot2 (round-1 style, which
// benched faster than the readlane variant).
__global__ __launch_bounds__(256, 2) void k_sim(
    const _Float16* __restrict__ PiF, const float* __restrict__ betaW,
    const float* __restrict__ sigmaW, const float* __restrict__ gammaW,
    const float* __restrict__ S0W, const float* __restrict__ E0W,
    const float* __restrict__ I0W, float* __restrict__ out) {
  const int b = blockIdx.x, m = threadIdx.x;
  __shared__ _Float16 stage[8192];  // 16 KB: 32 rows x 256 f16
  __shared__ _Float16 Ib[2][256];

  half2_t pi[128];
  {
    const _Float16* Pg = PiF + (size_t)b * 65536;
    for (int cc = 0; cc < 8; ++cc) {
#pragma unroll
      for (int i = 0; i < 4; ++i) {
        const int u = i * 256 + m;
        const int row = u >> 5, ch = u & 31;
        *(uint4*)(stage + row * 256 + ch * 8) =
            *(const uint4*)(Pg + (size_t)(cc * 32 + row) * 256 + ch * 8);
      }
      __syncthreads();
#pragma unroll
      for (int j = 0; j < 16; ++j)
        pi[cc * 16 + j] =
            half2_t{stage[(2 * j) * 256 + m], stage[(2 * j + 1) * 256 + m]};
      __syncthreads();
    }
  }

  const int base = b * 256 + m;
  const float bet = betaW[base], sig = sigmaW[base], gam = gammaW[base];
  float S = S0W[base], E = E0W[base], I = I0W[base];

  int p = 0;
  auto grads = [&](float Ss, float Es, float Is, float& dS, float& dE, float& dI) {
    Ib[p][m] = (_Float16)Is;
    __syncthreads();
    const half2_t* iv = (const half2_t*)Ib[p];
    float a0 = 0.f, a1 = 0.f, a2 = 0.f, a3 = 0.f;
#pragma unroll
    for (int t = 0; t < 128; t += 4) {
      a0 = fdot2(pi[t + 0], iv[t + 0], a0);
      a1 = fdot2(pi[t + 1], iv[t + 1], a1);
      a2 = fdot2(pi[t + 2], iv[t + 2], a2);
      a3 = fdot2(pi[t + 3], iv[t + 3], a3);
    }
    const float force = (a0 + a1) + (a2 + a3);
    p ^= 1;
    const float ninf = bet * Ss * force;
    const float sE = sig * Es;
    dS = -ninf;
    dE = ninf - sE;
    dI = sE - gam * Is;
  };

  float* outI = out + (size_t)b * (12 * 256) + m;
  float* outE = outI + 1572864;
  const float c6 = 0.25f / 6.f;

  for (int w = 0; w < 12; ++w) {
    for (int st = 0; st < 4; ++st) {
      float d1S, d1E, d1I, d2S, d2E, d2I, d3S, d3E, d3I, d4S, d4E, d4I;
      grads(S, E, I, d1S, d1E, d1I);
      grads(S + 0.125f * d1S, E + 0.125f * d1E, I + 0.125f * d1I, d2S, d2E, d2I);
      grads(S + 0.125f * d2S, E + 0.125f * d2E, I + 0.125f * d2I, d3S, d3E, d3I);
      grads(S + 0.25f * d3S, E + 0.25f * d3E, I + 0.25f * d3I, d4S, d4E, d4I);
      S = fminf(fmaxf(S + c6 * (d1S + 2.f * d2S + 2.f * d3S + d4S), 0.f), 1.f);
      E = fminf(fmaxf(E + c6 * (d1E + 2.f * d2E + 2.f * d3E + d4E), 0.f), 1.f);
      I = fminf(fmaxf(I + c6 * (d1I + 2.f * d2I + 2.f * d3I + d4I), 0.f), 1.f);
    }
    outI[w * 256] = I;
    outE[w * 256] = E;
  }
}

// ---------------- launch ---------------------------------------------------
extern "C" void kernel_launch(void* const* d_in, const int* in_sizes, int n_in,
                              void* d_out, int out_size, void* d_ws, size_t ws_size,
                              hipStream_t stream) {
  const float* x_hist = (const float*)d_in[0];
  const float* cnn    = (const float*)d_in[1];
  const float* W1     = (const float*)d_in[2];
  const float* b1     = (const float*)d_in[3];
  const float* W2     = (const float*)d_in[4];
  const float* b2     = (const float*)d_in[5];
  const float* M1     = (const float*)d_in[6];
  const float* mb1    = (const float*)d_in[7];
  const float* M2     = (const float*)d_in[8];
  const float* mb2    = (const float*)d_in[9];
  float* out = (float*)d_out;

  char* w = (char*)d_ws;
  _Float16* M2T     = (_Float16*)(w + 0);         // 16,777,216
  _Float16* hmf     = (_Float16*)(w + 16777216);  //    131,072
  float*    betaW   = (float*)(w + 16908288);     //    524,288 each
  float*    sigmaW  = (float*)(w + 17432576);
  float*    gammaW  = (float*)(w + 17956864);
  float*    S0W     = (float*)(w + 18481152);
  float*    E0W     = (float*)(w + 19005440);
  float*    I0W     = (float*)(w + 19529728);
  float*    pimpart = (float*)(w + 20054016);     //    262,144
  _Float16* PiF     = (_Float16*)(w + 20316160);  // 67,108,864 (end 87.4MB)
  // hpart/h alias the PiF region (dead before k_mobility2 writes PiF)
  float*    hpart   = (float*)(w + 20316160);     //  8,388,608
  float*    h       = (float*)(w + 28704768);     //    262,144

  hipMemsetAsync(pimpart, 0, 262144, stream);
  k_paramnet1<<<dim3(32, 16), 128, 0, stream>>>(x_hist, W1, hpart);
  k_paramnet2<<<256, 256, 0, stream>>>(hpart, b1, h);
  k_params_state<<<256, 256, 0, stream>>>(h, W2, b2, x_hist, betaW, sigmaW,
                                          gammaW, S0W, E0W, I0W);
  k_mobility1<<<512, 128, 0, stream>>>(cnn, M1, mb1, hmf);
  k_cvtM2<<<256, 256, 0, stream>>>(M2, M2T);
  k_mobility2<<<256, 512, 0, stream>>>(hmf, M2T, mb2, PiF, pimpart);
  k_finalize<<<259, 256, 0, stream>>>(betaW, sigmaW, gammaW, pimpart, out);
  k_sim<<<512, 256, 0, stream>>>(PiF, betaW, sigmaW, gammaW, S0W, E0W, I0W, out);
}

// Round 4
// 603.013 us; speedup vs baseline: 1.3780x; 1.1228x over previous
//
#include <hip/hip_runtime.h>
#include <hip/hip_bf16.h>
#include <stdint.h>
#include <stddef.h>

typedef _Float16 half2_t __attribute__((ext_vector_type(2)));
typedef _Float16 f16x8 __attribute__((ext_vector_type(8)));
typedef float f32x4 __attribute__((ext_vector_type(4)));

__device__ __forceinline__ float fdot2(half2_t a, half2_t b, float c) {
#if __has_builtin(__builtin_amdgcn_fdot2)
  return __builtin_amdgcn_fdot2(a, b, c, false);
#else
  return c + (float)a.x * (float)b.x + (float)a.y * (float)b.y;
#endif
}

// ---------------- param_net stage 1: partial h = X @ W1 (K-split) ----------
__global__ __launch_bounds__(128) void k_paramnet1(
    const float* __restrict__ X, const float* __restrict__ W1,
    float* __restrict__ hpart) {
  const int j = threadIdx.x;
  const int ks = blockIdx.x;
  const int b0 = blockIdx.y * 32;

  float w1r[128];
#pragma unroll
  for (int k = 0; k < 128; ++k)
    w1r[k] = W1[(size_t)(ks * 128 + k) * 128 + j];

  for (int bb = 0; bb < 32; ++bb) {
    const float* xr = X + (size_t)(b0 + bb) * 4096 + ks * 128;
    float a0 = 0.f, a1 = 0.f, a2 = 0.f, a3 = 0.f;
#pragma unroll
    for (int k = 0; k < 128; k += 4) {
      a0 = fmaf(w1r[k + 0], xr[k + 0], a0);
      a1 = fmaf(w1r[k + 1], xr[k + 1], a1);
      a2 = fmaf(w1r[k + 2], xr[k + 2], a2);
      a3 = fmaf(w1r[k + 3], xr[k + 3], a3);
    }
    hpart[((size_t)ks * 512 + (b0 + bb)) * 128 + j] = (a0 + a1) + (a2 + a3);
  }
}

// ---------------- param_net stage 2: reduce partials + bias + relu ---------
__global__ __launch_bounds__(256) void k_paramnet2(
    const float* __restrict__ hpart, const float* __restrict__ b1,
    float* __restrict__ h) {
  const int idx = blockIdx.x * 256 + threadIdx.x;
  float s = b1[idx & 127];
#pragma unroll
  for (int ks = 0; ks < 32; ++ks) s += hpart[(size_t)ks * 65536 + idx];
  h[idx] = fmaxf(s, 0.f);
}

// ---------------- params = h @ W2 + b2 -> sigmoids -> SEIR init state ------
__global__ __launch_bounds__(256) void k_params_state(
    const float* __restrict__ h, const float* __restrict__ W2,
    const float* __restrict__ b2, const float* __restrict__ X,
    float* __restrict__ betaW, float* __restrict__ sigmaW,
    float* __restrict__ gammaW, float* __restrict__ S0W,
    float* __restrict__ E0W, float* __restrict__ I0W) {
  const int b0 = blockIdx.x * 2;
  const int t = threadIdx.x;
  const float* h0 = h + (size_t)b0 * 128;
  const float* h1 = h0 + 128;
  float a00 = b2[t], a01 = b2[256 + t], a02 = b2[512 + t], a03 = b2[768 + t];
  float a10 = a00, a11 = a01, a12 = a02, a13 = a03;
#pragma unroll 2
  for (int k = 0; k < 128; ++k) {
    const float* wr = W2 + (size_t)k * 1024;
    const float w0 = wr[t], w1 = wr[256 + t], w2 = wr[512 + t], w3 = wr[768 + t];
    const float hv0 = h0[k], hv1 = h1[k];
    a00 = fmaf(hv0, w0, a00); a01 = fmaf(hv0, w1, a01);
    a02 = fmaf(hv0, w2, a02); a03 = fmaf(hv0, w3, a03);
    a10 = fmaf(hv1, w0, a10); a11 = fmaf(hv1, w1, a11);
    a12 = fmaf(hv1, w2, a12); a13 = fmaf(hv1, w3, a13);
  }
#pragma unroll
  for (int j = 0; j < 2; ++j) {
    const float p0 = j ? a10 : a00, p1 = j ? a11 : a01;
    const float p2 = j ? a12 : a02, p3 = j ? a13 : a03;
    const float beta = 3.f / (1.f + __expf(-p0));
    const float sig  = 1.f / (1.f + __expf(-p1));
    const float gam  = 1.f / (1.f + __expf(-p2));
    const float e0r  = 5.f / (1.f + __expf(-p3));
    const int base = (b0 + j) * 256 + t;
    const float I0 = fmaxf(X[(size_t)(b0 + j) * 4096 + 15 * 256 + t], 1e-6f);
    const float E0 = I0 * e0r;
    const float S0 = fmaxf(1.f - E0 - I0, 0.01f);
    betaW[base] = beta; sigmaW[base] = sig; gammaW[base] = gam;
    S0W[base] = S0; E0W[base] = E0; I0W[base] = I0;
  }
}

// ---------------- mobility stage 1: hm = relu(cnn @ M1 + mb1) as f16 -------
__global__ __launch_bounds__(128) void k_mobility1(
    const float* __restrict__ cnn, const float* __restrict__ M1,
    const float* __restrict__ mb1, _Float16* __restrict__ hmf) {
  const int b = blockIdx.x, j = threadIdx.x;
  const float* cr = cnn + b * 64;
  float a = mb1[j];
#pragma unroll
  for (int k = 0; k < 64; ++k) a = fmaf(cr[k], M1[k * 128 + j], a);
  hmf[b * 128 + j] = (_Float16)fmaxf(a, 0.f);
}

// ---------------- transpose M2 -> M2T[n][m][k] f16 -------------------------
__global__ __launch_bounds__(256) void k_cvtM2(
    const float* __restrict__ M2, _Float16* __restrict__ M2T) {
  const int n = blockIdx.x, m = threadIdx.x;
  half2_t row[64];
  const float* src = M2 + (size_t)n * 256 + m;
#pragma unroll 8
  for (int k2 = 0; k2 < 64; ++k2) {
    const float lo = src[(size_t)(2 * k2) * 65536];
    const float hi = src[(size_t)(2 * k2 + 1) * 65536];
    row[k2] = half2_t{(_Float16)lo, (_Float16)hi};
  }
  uint4* dst = (uint4*)(M2T + ((size_t)n * 256 + m) * 128);
  const uint4* s4 = (const uint4*)row;
#pragma unroll
  for (int i = 0; i < 16; ++i) dst[i] = s4[i];
}

// ---------------- mobility stage 2: MFMA GEMM + in-register softmax --------
__global__ __launch_bounds__(512, 2) void k_mobility2(
    const _Float16* __restrict__ hmf, const _Float16* __restrict__ M2T,
    const float* __restrict__ mb2, _Float16* __restrict__ PiF,
    float* __restrict__ pimpart) {
  const int n = blockIdx.x;
  const int tid = threadIdx.x;
  const int wave = tid >> 6;
  const int lane = tid & 63;
  const int q = lane >> 4;
  const int c = lane & 15;

  __shared__ _Float16 sm[8][16 * 256];  // 64 KB, wave-private slots

  const _Float16* Bbase = M2T + (size_t)n * 32768 + (size_t)c * 128 + q * 8;
  const float* mbp = mb2 + n * 256 + c;

  for (int pass = 0; pass < 2; ++pass) {
    const int bt0 = wave * 4 + pass * 2;
    f32x4 C0[16], C1[16];
#pragma unroll
    for (int nb = 0; nb < 16; ++nb) {
      const float mbv = mbp[nb * 16];
      C0[nb] = f32x4{mbv, mbv, mbv, mbv};
      C1[nb] = C0[nb];
    }
    const _Float16* A0 = hmf + (size_t)(bt0 * 16 + c) * 128 + q * 8;
    const _Float16* A1 = A0 + 16 * 128;
#pragma unroll
    for (int ks = 0; ks < 4; ++ks) {
      const f16x8 Af0 = *(const f16x8*)(A0 + ks * 32);
      const f16x8 Af1 = *(const f16x8*)(A1 + ks * 32);
#pragma unroll
      for (int nb = 0; nb < 16; ++nb) {
        const f16x8 Bf = *(const f16x8*)(Bbase + nb * 2048 + ks * 32);
        C0[nb] = __builtin_amdgcn_mfma_f32_16x16x32_f16(Af0, Bf, C0[nb], 0, 0, 0);
        C1[nb] = __builtin_amdgcn_mfma_f32_16x16x32_f16(Af1, Bf, C1[nb], 0, 0, 0);
      }
    }

    float colsum[16];
#pragma unroll
    for (int nb = 0; nb < 16; ++nb) colsum[nb] = 0.f;

#pragma unroll
    for (int half = 0; half < 2; ++half) {
      f32x4* C = half ? C1 : C0;
      const int bt = bt0 + half;
      float mx[4], sum[4];
#pragma unroll
      for (int r = 0; r < 4; ++r) mx[r] = C[0][r];
#pragma unroll
      for (int nb = 1; nb < 16; ++nb)
#pragma unroll
        for (int r = 0; r < 4; ++r) mx[r] = fmaxf(mx[r], C[nb][r]);
#pragma unroll
      for (int r = 0; r < 4; ++r) {
        mx[r] = fmaxf(mx[r], __shfl_xor(mx[r], 1, 16));
        mx[r] = fmaxf(mx[r], __shfl_xor(mx[r], 2, 16));
        mx[r] = fmaxf(mx[r], __shfl_xor(mx[r], 4, 16));
        mx[r] = fmaxf(mx[r], __shfl_xor(mx[r], 8, 16));
        sum[r] = 0.f;
      }
#pragma unroll
      for (int nb = 0; nb < 16; ++nb)
#pragma unroll
        for (int r = 0; r < 4; ++r) {
          const float e = __expf(C[nb][r] - mx[r]);
          C[nb][r] = e;
          sum[r] += e;
        }
#pragma unroll
      for (int r = 0; r < 4; ++r) {
        sum[r] += __shfl_xor(sum[r], 1, 16);
        sum[r] += __shfl_xor(sum[r], 2, 16);
        sum[r] += __shfl_xor(sum[r], 4, 16);
        sum[r] += __shfl_xor(sum[r], 8, 16);
        sum[r] = 1.f / sum[r];
      }
      _Float16* slot = sm[wave];
#pragma unroll
      for (int nb = 0; nb < 16; ++nb) {
#pragma unroll
        for (int r = 0; r < 4; ++r) {
          const float v = C[nb][r] * sum[r];
          colsum[nb] += v;
          slot[(q * 4 + r) * 256 + nb * 16 + c] = (_Float16)v;
        }
      }
      const int l2 = lane & 31, rh = lane >> 5;
      _Float16* Pg = PiF + ((size_t)(bt * 16) * 256 + n) * 256;
#pragma unroll
      for (int i = 0; i < 8; ++i) {
        const int row = i * 2 + rh;
        const uint4 v = *(const uint4*)(slot + row * 256 + l2 * 8);
        *(uint4*)(Pg + (size_t)row * 65536 + l2 * 8) = v;
      }
    }
#pragma unroll
    for (int nb = 0; nb < 16; ++nb) {
      colsum[nb] += __shfl_xor(colsum[nb], 16);
      colsum[nb] += __shfl_xor(colsum[nb], 32);
    }
    if (lane < 16) {
      float* pp = pimpart + n * 256 + lane;
#pragma unroll
      for (int nb = 0; nb < 16; ++nb) atomicAdd(pp + nb * 16, colsum[nb]);
    }
  }
}

// ---------------- means of beta/sigma/gamma and Pi ------------------------
__global__ __launch_bounds__(256) void k_finalize(
    const float* __restrict__ betaW, const float* __restrict__ sigmaW,
    const float* __restrict__ gammaW, const float* __restrict__ pimpart,
    float* __restrict__ out) {
  const int idx = blockIdx.x * 256 + threadIdx.x;
  const float inv = 1.f / 512.f;
  if (idx < 768) {
    const float* src = (idx < 256) ? betaW : (idx < 512) ? sigmaW : gammaW;
    const int t = idx & 255;
    float s = 0.f;
    for (int bb = 0; bb < 512; ++bb) s += src[bb * 256 + t];
    out[3145728 + idx] = s * inv;
  } else {
    const int pm = idx - 768;
    out[3146496 + pm] = pimpart[pm] * inv;
  }
}

// ---------------- SEIR RK4 simulation -------------------------------------
// Startup: LDS-tiled transpose of Pi[b] into per-thread column regs.
// Inner loop: PIPE-BALANCED I-broadcast. Round-3 (pure ds_read broadcast)
// was DS-bound: 32 b128/wave/stage x 12cyc x 8 waves/CU = 3072 cyc/stage
// => 246us (matches 263 measured). Now: chunks 0-7 via 8 broadcast
// ds_read_b128, chunks 8-31 via 1 per-lane ds_read_b128 + v_readlane
// (VALU) feeding v_dot2 SGPR operand. DS ~864 cyc/CU/stage, VALU ~950
// cyc/SIMD/stage -> ~80us predicted.
__global__ __launch_bounds__(256, 2) void k_sim(
    const _Float16* __restrict__ PiF, const float* __restrict__ betaW,
    const float* __restrict__ sigmaW, const float* __restrict__ gammaW,
    const float* __restrict__ S0W, const float* __restrict__ E0W,
    const float* __restrict__ I0W, float* __restrict__ out) {
  const int b = blockIdx.x, m = threadIdx.x;
  __shared__ _Float16 stage[8192];  // 16 KB: 32 rows x 256 f16
  __shared__ _Float16 Ib[2][256];

  half2_t pi[128];
  {
    const _Float16* Pg = PiF + (size_t)b * 65536;
    for (int cc = 0; cc < 8; ++cc) {
#pragma unroll
      for (int i = 0; i < 4; ++i) {
        const int u = i * 256 + m;
        const int row = u >> 5, ch = u & 31;
        *(uint4*)(stage + row * 256 + ch * 8) =
            *(const uint4*)(Pg + (size_t)(cc * 32 + row) * 256 + ch * 8);
      }
      __syncthreads();
#pragma unroll
      for (int j = 0; j < 16; ++j)
        pi[cc * 16 + j] =
            half2_t{stage[(2 * j) * 256 + m], stage[(2 * j + 1) * 256 + m]};
      __syncthreads();
    }
  }

  const int base = b * 256 + m;
  const float bet = betaW[base], sig = sigmaW[base], gam = gammaW[base];
  float S = S0W[base], E = E0W[base], I = I0W[base];
  const int chunk = m & 31;

  int p = 0;
  auto grads = [&](float Ss, float Es, float Is, float& dS, float& dE, float& dI) {
    Ib[p][m] = (_Float16)Is;
    __syncthreads();
    const uint4* ivq = (const uint4*)Ib[p];
    const uint4 v = ivq[chunk];            // per-lane chunk for readlane part
    const half2_t* iv = (const half2_t*)Ib[p];
    p ^= 1;
    float a0 = 0.f, a1 = 0.f, a2 = 0.f, a3 = 0.f;
    // chunks 0..7 via broadcast ds_read_b128 (DS pipe)
#pragma unroll
    for (int t = 0; t < 32; t += 4) {
      a0 = fdot2(pi[t + 0], iv[t + 0], a0);
      a1 = fdot2(pi[t + 1], iv[t + 1], a1);
      a2 = fdot2(pi[t + 2], iv[t + 2], a2);
      a3 = fdot2(pi[t + 3], iv[t + 3], a3);
    }
    // chunks 8..31 via v_readlane (VALU pipe)
#pragma unroll
    for (int c = 8; c < 32; ++c) {
      const uint32_t s0 = __builtin_amdgcn_readlane(v.x, c);
      const uint32_t s1 = __builtin_amdgcn_readlane(v.y, c);
      const uint32_t s2 = __builtin_amdgcn_readlane(v.z, c);
      const uint32_t s3 = __builtin_amdgcn_readlane(v.w, c);
      a0 = fdot2(pi[c * 4 + 0], __builtin_bit_cast(half2_t, s0), a0);
      a1 = fdot2(pi[c * 4 + 1], __builtin_bit_cast(half2_t, s1), a1);
      a2 = fdot2(pi[c * 4 + 2], __builtin_bit_cast(half2_t, s2), a2);
      a3 = fdot2(pi[c * 4 + 3], __builtin_bit_cast(half2_t, s3), a3);
    }
    const float force = (a0 + a1) + (a2 + a3);
    const float ninf = bet * Ss * force;
    const float sE = sig * Es;
    dS = -ninf;
    dE = ninf - sE;
    dI = sE - gam * Is;
  };

  float* outI = out + (size_t)b * (12 * 256) + m;
  float* outE = outI + 1572864;
  const float c6 = 0.25f / 6.f;

  for (int w = 0; w < 12; ++w) {
    for (int st = 0; st < 4; ++st) {
      float d1S, d1E, d1I, d2S, d2E, d2I, d3S, d3E, d3I, d4S, d4E, d4I;
      grads(S, E, I, d1S, d1E, d1I);
      grads(S + 0.125f * d1S, E + 0.125f * d1E, I + 0.125f * d1I, d2S, d2E, d2I);
      grads(S + 0.125f * d2S, E + 0.125f * d2E, I + 0.125f * d2I, d3S, d3E, d3I);
      grads(S + 0.25f * d3S, E + 0.25f * d3E, I + 0.25f * d3I, d4S, d4E, d4I);
      S = fminf(fmaxf(S + c6 * (d1S + 2.f * d2S + 2.f * d3S + d4S), 0.f), 1.f);
      E = fminf(fmaxf(E + c6 * (d1E + 2.f * d2E + 2.f * d3E + d4E), 0.f), 1.f);
      I = fminf(fmaxf(I + c6 * (d1I + 2.f * d2I + 2.f * d3I + d4I), 0.f), 1.f);
    }
    outI[w * 256] = I;
    outE[w * 256] = E;
  }
}

// ---------------- launch ---------------------------------------------------
extern "C" void kernel_launch(void* const* d_in, const int* in_sizes, int n_in,
                              void* d_out, int out_size, void* d_ws, size_t ws_size,
                              hipStream_t stream) {
  const float* x_hist = (const float*)d_in[0];
  const float* cnn    = (const float*)d_in[1];
  const float* W1     = (const float*)d_in[2];
  const float* b1     = (const float*)d_in[3];
  const float* W2     = (const float*)d_in[4];
  const float* b2     = (const float*)d_in[5];
  const float* M1     = (const float*)d_in[6];
  const float* mb1    = (const float*)d_in[7];
  const float* M2     = (const float*)d_in[8];
  const float* mb2    = (const float*)d_in[9];
  float* out = (float*)d_out;

  char* w = (char*)d_ws;
  _Float16* M2T     = (_Float16*)(w + 0);         // 16,777,216
  _Float16* hmf     = (_Float16*)(w + 16777216);  //    131,072
  float*    betaW   = (float*)(w + 16908288);     //    524,288 each
  float*    sigmaW  = (float*)(w + 17432576);
  float*    gammaW  = (float*)(w + 17956864);
  float*    S0W     = (float*)(w + 18481152);
  float*    E0W     = (float*)(w + 19005440);
  float*    I0W     = (float*)(w + 19529728);
  float*    pimpart = (float*)(w + 20054016);     //    262,144
  _Float16* PiF     = (_Float16*)(w + 20316160);  // 67,108,864 (end 87.4MB)
  // hpart/h alias the PiF region (dead before k_mobility2 writes PiF)
  float*    hpart   = (float*)(w + 20316160);     //  8,388,608
  float*    h       = (float*)(w + 28704768);     //    262,144

  hipMemsetAsync(pimpart, 0, 262144, stream);
  k_paramnet1<<<dim3(32, 16), 128, 0, stream>>>(x_hist, W1, hpart);
  k_paramnet2<<<256, 256, 0, stream>>>(hpart, b1, h);
  k_params_state<<<256, 256, 0, stream>>>(h, W2, b2, x_hist, betaW, sigmaW,
                                          gammaW, S0W, E0W, I0W);
  k_mobility1<<<512, 128, 0, stream>>>(cnn, M1, mb1, hmf);
  k_cvtM2<<<256, 256, 0, stream>>>(M2, M2T);
  k_mobility2<<<256, 512, 0, stream>>>(hmf, M2T, mb2, PiF, pimpart);
  k_finalize<<<259, 256, 0, stream>>>(betaW, sigmaW, gammaW, pimpart, out);
  k_sim<<<512, 256, 0, stream>>>(PiF, betaW, sigmaW, gammaW, S0W, E0W, I0W, out);
}

// Round 5
// 508.945 us; speedup vs baseline: 1.6326x; 1.1848x over previous
//
#include <hip/hip_runtime.h>
#include <hip/hip_bf16.h>
#include <stdint.h>
#include <stddef.h>

typedef _Float16 half2_t __attribute__((ext_vector_type(2)));
typedef _Float16 f16x8 __attribute__((ext_vector_type(8)));
typedef float f32x4 __attribute__((ext_vector_type(4)));

__device__ __forceinline__ float fdot2(half2_t a, half2_t b, float c) {
#if __has_builtin(__builtin_amdgcn_fdot2)
  return __builtin_amdgcn_fdot2(a, b, c, false);
#else
  return c + (float)a.x * (float)b.x + (float)a.y * (float)b.y;
#endif
}

// ---------------- param_net stage 1: partial h = X @ W1 (K-split) ----------
__global__ __launch_bounds__(128) void k_paramnet1(
    const float* __restrict__ X, const float* __restrict__ W1,
    float* __restrict__ hpart) {
  const int j = threadIdx.x;
  const int ks = blockIdx.x;
  const int b0 = blockIdx.y * 32;

  float w1r[128];
#pragma unroll
  for (int k = 0; k < 128; ++k)
    w1r[k] = W1[(size_t)(ks * 128 + k) * 128 + j];

  for (int bb = 0; bb < 32; ++bb) {
    const float* xr = X + (size_t)(b0 + bb) * 4096 + ks * 128;
    float a0 = 0.f, a1 = 0.f, a2 = 0.f, a3 = 0.f;
#pragma unroll
    for (int k = 0; k < 128; k += 4) {
      a0 = fmaf(w1r[k + 0], xr[k + 0], a0);
      a1 = fmaf(w1r[k + 1], xr[k + 1], a1);
      a2 = fmaf(w1r[k + 2], xr[k + 2], a2);
      a3 = fmaf(w1r[k + 3], xr[k + 3], a3);
    }
    hpart[((size_t)ks * 512 + (b0 + bb)) * 128 + j] = (a0 + a1) + (a2 + a3);
  }
}

// ---------------- param_net stage 2: reduce partials + bias + relu ---------
__global__ __launch_bounds__(256) void k_paramnet2(
    const float* __restrict__ hpart, const float* __restrict__ b1,
    float* __restrict__ h) {
  const int idx = blockIdx.x * 256 + threadIdx.x;
  float s = b1[idx & 127];
#pragma unroll
  for (int ks = 0; ks < 32; ++ks) s += hpart[(size_t)ks * 65536 + idx];
  h[idx] = fmaxf(s, 0.f);
}

// ---------------- params = h @ W2 + b2 -> sigmoids -> state + stat partials
__global__ __launch_bounds__(256) void k_params_state(
    const float* __restrict__ h, const float* __restrict__ W2,
    const float* __restrict__ b2, const float* __restrict__ X,
    float* __restrict__ betaW, float* __restrict__ sigmaW,
    float* __restrict__ gammaW, float* __restrict__ S0W,
    float* __restrict__ E0W, float* __restrict__ I0W,
    float* __restrict__ stats) {
  const int b0 = blockIdx.x * 2;
  const int t = threadIdx.x;
  const float* h0 = h + (size_t)b0 * 128;
  const float* h1 = h0 + 128;
  float a00 = b2[t], a01 = b2[256 + t], a02 = b2[512 + t], a03 = b2[768 + t];
  float a10 = a00, a11 = a01, a12 = a02, a13 = a03;
#pragma unroll 2
  for (int k = 0; k < 128; ++k) {
    const float* wr = W2 + (size_t)k * 1024;
    const float w0 = wr[t], w1 = wr[256 + t], w2 = wr[512 + t], w3 = wr[768 + t];
    const float hv0 = h0[k], hv1 = h1[k];
    a00 = fmaf(hv0, w0, a00); a01 = fmaf(hv0, w1, a01);
    a02 = fmaf(hv0, w2, a02); a03 = fmaf(hv0, w3, a03);
    a10 = fmaf(hv1, w0, a10); a11 = fmaf(hv1, w1, a11);
    a12 = fmaf(hv1, w2, a12); a13 = fmaf(hv1, w3, a13);
  }
  float bsum = 0.f, ssum = 0.f, gsum = 0.f;
#pragma unroll
  for (int j = 0; j < 2; ++j) {
    const float p0 = j ? a10 : a00, p1 = j ? a11 : a01;
    const float p2 = j ? a12 : a02, p3 = j ? a13 : a03;
    const float beta = 3.f / (1.f + __expf(-p0));
    const float sig  = 1.f / (1.f + __expf(-p1));
    const float gam  = 1.f / (1.f + __expf(-p2));
    const float e0r  = 5.f / (1.f + __expf(-p3));
    const int base = (b0 + j) * 256 + t;
    const float I0 = fmaxf(X[(size_t)(b0 + j) * 4096 + 15 * 256 + t], 1e-6f);
    const float E0 = I0 * e0r;
    const float S0 = fmaxf(1.f - E0 - I0, 0.01f);
    betaW[base] = beta; sigmaW[base] = sig; gammaW[base] = gam;
    S0W[base] = S0; E0W[base] = E0; I0W[base] = I0;
    bsum += beta; ssum += sig; gsum += gam;
  }
  atomicAdd(stats + t, bsum);
  atomicAdd(stats + 256 + t, ssum);
  atomicAdd(stats + 512 + t, gsum);
}

// ---------------- mobility stage 1: hm = relu(cnn @ M1 + mb1) as f16 -------
__global__ __launch_bounds__(128) void k_mobility1(
    const float* __restrict__ cnn, const float* __restrict__ M1,
    const float* __restrict__ mb1, _Float16* __restrict__ hmf) {
  const int b = blockIdx.x, j = threadIdx.x;
  const float* cr = cnn + b * 64;
  float a = mb1[j];
#pragma unroll
  for (int k = 0; k < 64; ++k) a = fmaf(cr[k], M1[k * 128 + j], a);
  hmf[b * 128 + j] = (_Float16)fmaxf(a, 0.f);
}

// ---------------- transpose M2 -> M2T[n][m][k] f16 (k-split x4) ------------
__global__ __launch_bounds__(256) void k_cvtM2(
    const float* __restrict__ M2, _Float16* __restrict__ M2T) {
  const int n = blockIdx.x, m = threadIdx.x, kq = blockIdx.y;
  half2_t row[16];
  const float* src = M2 + (size_t)n * 256 + m;
#pragma unroll
  for (int i = 0; i < 16; ++i) {
    const int k2 = kq * 16 + i;
    const float lo = src[(size_t)(2 * k2) * 65536];
    const float hi = src[(size_t)(2 * k2 + 1) * 65536];
    row[i] = half2_t{(_Float16)lo, (_Float16)hi};
  }
  uint4* dst = (uint4*)(M2T + ((size_t)n * 256 + m) * 128 + kq * 32);
  const uint4* s4 = (const uint4*)row;
#pragma unroll
  for (int i = 0; i < 4; ++i) dst[i] = s4[i];
}

// ---------------- mobility stage 2: MFMA GEMM + in-register softmax --------
// grid (256 n, 2 pass): pass split across blocks -> 2 blocks/CU, half the
// straight-line body (I-fetch + latency hiding).
__global__ __launch_bounds__(512, 2) void k_mobility2(
    const _Float16* __restrict__ hmf, const _Float16* __restrict__ M2T,
    const float* __restrict__ mb2, _Float16* __restrict__ PiF,
    float* __restrict__ pimpart) {
  const int n = blockIdx.x;
  const int pass = blockIdx.y;
  const int tid = threadIdx.x;
  const int wave = tid >> 6;
  const int lane = tid & 63;
  const int q = lane >> 4;
  const int c = lane & 15;

  __shared__ _Float16 sm[8][16 * 256];  // 64 KB, wave-private slots

  const _Float16* Bbase = M2T + (size_t)n * 32768 + (size_t)c * 128 + q * 8;
  const float* mbp = mb2 + n * 256 + c;

  const int bt0 = wave * 4 + pass * 2;
  f32x4 C0[16], C1[16];
#pragma unroll
  for (int nb = 0; nb < 16; ++nb) {
    const float mbv = mbp[nb * 16];
    C0[nb] = f32x4{mbv, mbv, mbv, mbv};
    C1[nb] = C0[nb];
  }
  const _Float16* A0 = hmf + (size_t)(bt0 * 16 + c) * 128 + q * 8;
  const _Float16* A1 = A0 + 16 * 128;
#pragma unroll
  for (int ks = 0; ks < 4; ++ks) {
    const f16x8 Af0 = *(const f16x8*)(A0 + ks * 32);
    const f16x8 Af1 = *(const f16x8*)(A1 + ks * 32);
#pragma unroll
    for (int nb = 0; nb < 16; ++nb) {
      const f16x8 Bf = *(const f16x8*)(Bbase + nb * 2048 + ks * 32);
      C0[nb] = __builtin_amdgcn_mfma_f32_16x16x32_f16(Af0, Bf, C0[nb], 0, 0, 0);
      C1[nb] = __builtin_amdgcn_mfma_f32_16x16x32_f16(Af1, Bf, C1[nb], 0, 0, 0);
    }
  }

  float colsum[16];
#pragma unroll
  for (int nb = 0; nb < 16; ++nb) colsum[nb] = 0.f;

#pragma unroll
  for (int half = 0; half < 2; ++half) {
    f32x4* C = half ? C1 : C0;
    const int bt = bt0 + half;
    float mx[4], sum[4];
#pragma unroll
    for (int r = 0; r < 4; ++r) mx[r] = C[0][r];
#pragma unroll
    for (int nb = 1; nb < 16; ++nb)
#pragma unroll
      for (int r = 0; r < 4; ++r) mx[r] = fmaxf(mx[r], C[nb][r]);
#pragma unroll
    for (int r = 0; r < 4; ++r) {
      mx[r] = fmaxf(mx[r], __shfl_xor(mx[r], 1, 16));
      mx[r] = fmaxf(mx[r], __shfl_xor(mx[r], 2, 16));
      mx[r] = fmaxf(mx[r], __shfl_xor(mx[r], 4, 16));
      mx[r] = fmaxf(mx[r], __shfl_xor(mx[r], 8, 16));
      sum[r] = 0.f;
    }
#pragma unroll
    for (int nb = 0; nb < 16; ++nb)
#pragma unroll
      for (int r = 0; r < 4; ++r) {
        const float e = __expf(C[nb][r] - mx[r]);
        C[nb][r] = e;
        sum[r] += e;
      }
#pragma unroll
    for (int r = 0; r < 4; ++r) {
      sum[r] += __shfl_xor(sum[r], 1, 16);
      sum[r] += __shfl_xor(sum[r], 2, 16);
      sum[r] += __shfl_xor(sum[r], 4, 16);
      sum[r] += __shfl_xor(sum[r], 8, 16);
      sum[r] = 1.f / sum[r];
    }
    _Float16* slot = sm[wave];
#pragma unroll
    for (int nb = 0; nb < 16; ++nb) {
#pragma unroll
      for (int r = 0; r < 4; ++r) {
        const float v = C[nb][r] * sum[r];
        colsum[nb] += v;
        slot[(q * 4 + r) * 256 + nb * 16 + c] = (_Float16)v;
      }
    }
    const int l2 = lane & 31, rh = lane >> 5;
    _Float16* Pg = PiF + ((size_t)(bt * 16) * 256 + n) * 256;
#pragma unroll
    for (int i = 0; i < 8; ++i) {
      const int row = i * 2 + rh;
      const uint4 v = *(const uint4*)(slot + row * 256 + l2 * 8);
      *(uint4*)(Pg + (size_t)row * 65536 + l2 * 8) = v;
    }
  }
#pragma unroll
  for (int nb = 0; nb < 16; ++nb) {
    colsum[nb] += __shfl_xor(colsum[nb], 16);
    colsum[nb] += __shfl_xor(colsum[nb], 32);
  }
  if (lane < 16) {
    float* pp = pimpart + n * 256 + lane;
#pragma unroll
    for (int nb = 0; nb < 16; ++nb) atomicAdd(pp + nb * 16, colsum[nb]);
  }
}

// ---------------- means: scale stats + Pi-mean partials --------------------
__global__ __launch_bounds__(256) void k_finalize(
    const float* __restrict__ stats, const float* __restrict__ pimpart,
    float* __restrict__ out) {
  const int idx = blockIdx.x * 256 + threadIdx.x;
  const float inv = 1.f / 512.f;
  if (idx < 768) {
    out[3145728 + idx] = stats[idx] * inv;
  } else {
    const int pm = idx - 768;
    out[3146496 + pm] = pimpart[pm] * inv;
  }
}

// ---------------- SEIR RK4 simulation -------------------------------------
// 16/16 pipe-balanced I-broadcast: chunks 0-15 broadcast ds_read_b128,
// chunks 16-31 v_readlane (lane j holds chunk 16+j). Round-4 (8/24) was
// VALU-bound at 74%; trading 32 readlanes for 8 ds_reads rebalances.
__global__ __launch_bounds__(256, 2) void k_sim(
    const _Float16* __restrict__ PiF, const float* __restrict__ betaW,
    const float* __restrict__ sigmaW, const float* __restrict__ gammaW,
    const float* __restrict__ S0W, const float* __restrict__ E0W,
    const float* __restrict__ I0W, float* __restrict__ out) {
  const int b = blockIdx.x, m = threadIdx.x;
  __shared__ _Float16 stage[8192];  // 16 KB: 32 rows x 256 f16
  __shared__ _Float16 Ib[2][256];

  half2_t pi[128];
  {
    const _Float16* Pg = PiF + (size_t)b * 65536;
    for (int cc = 0; cc < 8; ++cc) {
#pragma unroll
      for (int i = 0; i < 4; ++i) {
        const int u = i * 256 + m;
        const int row = u >> 5, ch = u & 31;
        *(uint4*)(stage + row * 256 + ch * 8) =
            *(const uint4*)(Pg + (size_t)(cc * 32 + row) * 256 + ch * 8);
      }
      __syncthreads();
#pragma unroll
      for (int j = 0; j < 16; ++j)
        pi[cc * 16 + j] =
            half2_t{stage[(2 * j) * 256 + m], stage[(2 * j + 1) * 256 + m]};
      __syncthreads();
    }
  }

  const int base = b * 256 + m;
  const float bet = betaW[base], sig = sigmaW[base], gam = gammaW[base];
  float S = S0W[base], E = E0W[base], I = I0W[base];
  const int mychunk = 16 + (m & 15);

  int p = 0;
  auto grads = [&](float Ss, float Es, float Is, float& dS, float& dE, float& dI) {
    Ib[p][m] = (_Float16)Is;
    __syncthreads();
    const uint4* ivq = (const uint4*)Ib[p];
    const uint4 v = ivq[mychunk];          // lane j holds chunk 16+j
    const half2_t* iv = (const half2_t*)Ib[p];
    p ^= 1;
    float a0 = 0.f, a1 = 0.f, a2 = 0.f, a3 = 0.f;
    // chunks 0..15 via broadcast ds_read_b128 (DS pipe)
#pragma unroll
    for (int t = 0; t < 64; t += 4) {
      a0 = fdot2(pi[t + 0], iv[t + 0], a0);
      a1 = fdot2(pi[t + 1], iv[t + 1], a1);
      a2 = fdot2(pi[t + 2], iv[t + 2], a2);
      a3 = fdot2(pi[t + 3], iv[t + 3], a3);
    }
    // chunks 16..31 via v_readlane (VALU pipe)
#pragma unroll
    for (int j = 0; j < 16; ++j) {
      const uint32_t s0 = __builtin_amdgcn_readlane(v.x, j);
      const uint32_t s1 = __builtin_amdgcn_readlane(v.y, j);
      const uint32_t s2 = __builtin_amdgcn_readlane(v.z, j);
      const uint32_t s3 = __builtin_amdgcn_readlane(v.w, j);
      const int t = 64 + j * 4;
      a0 = fdot2(pi[t + 0], __builtin_bit_cast(half2_t, s0), a0);
      a1 = fdot2(pi[t + 1], __builtin_bit_cast(half2_t, s1), a1);
      a2 = fdot2(pi[t + 2], __builtin_bit_cast(half2_t, s2), a2);
      a3 = fdot2(pi[t + 3], __builtin_bit_cast(half2_t, s3), a3);
    }
    const float force = (a0 + a1) + (a2 + a3);
    const float ninf = bet * Ss * force;
    const float sE = sig * Es;
    dS = -ninf;
    dE = ninf - sE;
    dI = sE - gam * Is;
  };

  float* outI = out + (size_t)b * (12 * 256) + m;
  float* outE = outI + 1572864;
  const float c6 = 0.25f / 6.f;

  for (int w = 0; w < 12; ++w) {
    for (int st = 0; st < 4; ++st) {
      float d1S, d1E, d1I, d2S, d2E, d2I, d3S, d3E, d3I, d4S, d4E, d4I;
      grads(S, E, I, d1S, d1E, d1I);
      grads(S + 0.125f * d1S, E + 0.125f * d1E, I + 0.125f * d1I, d2S, d2E, d2I);
      grads(S + 0.125f * d2S, E + 0.125f * d2E, I + 0.125f * d2I, d3S, d3E, d3I);
      grads(S + 0.25f * d3S, E + 0.25f * d3E, I + 0.25f * d3I, d4S, d4E, d4I);
      S = fminf(fmaxf(S + c6 * (d1S + 2.f * d2S + 2.f * d3S + d4S), 0.f), 1.f);
      E = fminf(fmaxf(E + c6 * (d1E + 2.f * d2E + 2.f * d3E + d4E), 0.f), 1.f);
      I = fminf(fmaxf(I + c6 * (d1I + 2.f * d2I + 2.f * d3I + d4I), 0.f), 1.f);
    }
    outI[w * 256] = I;
    outE[w * 256] = E;
  }
}

// ---------------- launch ---------------------------------------------------
extern "C" void kernel_launch(void* const* d_in, const int* in_sizes, int n_in,
                              void* d_out, int out_size, void* d_ws, size_t ws_size,
                              hipStream_t stream) {
  const float* x_hist = (const float*)d_in[0];
  const float* cnn    = (const float*)d_in[1];
  const float* W1     = (const float*)d_in[2];
  const float* b1     = (const float*)d_in[3];
  const float* W2     = (const float*)d_in[4];
  const float* b2     = (const float*)d_in[5];
  const float* M1     = (const float*)d_in[6];
  const float* mb1    = (const float*)d_in[7];
  const float* M2     = (const float*)d_in[8];
  const float* mb2    = (const float*)d_in[9];
  float* out = (float*)d_out;

  char* w = (char*)d_ws;
  _Float16* M2T     = (_Float16*)(w + 0);         // 16,777,216
  _Float16* hmf     = (_Float16*)(w + 16777216);  //    131,072
  float*    betaW   = (float*)(w + 16908288);     //    524,288 each
  float*    sigmaW  = (float*)(w + 17432576);
  float*    gammaW  = (float*)(w + 17956864);
  float*    S0W     = (float*)(w + 18481152);
  float*    E0W     = (float*)(w + 19005440);
  float*    I0W     = (float*)(w + 19529728);
  float*    pimpart = (float*)(w + 20054016);     //    262,144
  float*    stats   = (float*)(w + 20316160);     //      4,096 (768 used)
  _Float16* PiF     = (_Float16*)(w + 20320256);  // 67,108,864 (end 87.4MB)
  // hpart/h alias the PiF region (dead before k_mobility2 writes PiF)
  float*    hpart   = (float*)(w + 20320256);     //  8,388,608
  float*    h       = (float*)(w + 28708864);     //    262,144

  hipMemsetAsync(pimpart, 0, 266240, stream);  // pimpart + stats
  k_paramnet1<<<dim3(32, 16), 128, 0, stream>>>(x_hist, W1, hpart);
  k_paramnet2<<<256, 256, 0, stream>>>(hpart, b1, h);
  k_params_state<<<256, 256, 0, stream>>>(h, W2, b2, x_hist, betaW, sigmaW,
                                          gammaW, S0W, E0W, I0W, stats);
  k_mobility1<<<512, 128, 0, stream>>>(cnn, M1, mb1, hmf);
  k_cvtM2<<<dim3(256, 4), 256, 0, stream>>>(M2, M2T);
  k_mobility2<<<dim3(256, 2), 512, 0, stream>>>(hmf, M2T, mb2, PiF, pimpart);
  k_finalize<<<259, 256, 0, stream>>>(stats, pimpart, out);
  k_sim<<<512, 256, 0, stream>>>(PiF, betaW, sigmaW, gammaW, S0W, E0W, I0W, out);
}

// Round 6
// 456.671 us; speedup vs baseline: 1.8195x; 1.1145x over previous
//
#include <hip/hip_runtime.h>
#include <hip/hip_bf16.h>
#include <stdint.h>
#include <stddef.h>

typedef _Float16 half2_t __attribute__((ext_vector_type(2)));
typedef _Float16 f16x8 __attribute__((ext_vector_type(8)));
typedef float f32x4 __attribute__((ext_vector_type(4)));

__device__ __forceinline__ float fdot2(half2_t a, half2_t b, float c) {
#if __has_builtin(__builtin_amdgcn_fdot2)
  return __builtin_amdgcn_fdot2(a, b, c, false);
#else
  return c + (float)a.x * (float)b.x + (float)a.y * (float)b.y;
#endif
}

// ---------------- param_net stage 1: partial h = X @ W1 (K-split) ----------
__global__ __launch_bounds__(128) void k_paramnet1(
    const float* __restrict__ X, const float* __restrict__ W1,
    float* __restrict__ hpart) {
  const int j = threadIdx.x;
  const int ks = blockIdx.x;
  const int b0 = blockIdx.y * 32;

  float w1r[128];
#pragma unroll
  for (int k = 0; k < 128; ++k)
    w1r[k] = W1[(size_t)(ks * 128 + k) * 128 + j];

  for (int bb = 0; bb < 32; ++bb) {
    const float* xr = X + (size_t)(b0 + bb) * 4096 + ks * 128;
    float a0 = 0.f, a1 = 0.f, a2 = 0.f, a3 = 0.f;
#pragma unroll
    for (int k = 0; k < 128; k += 4) {
      a0 = fmaf(w1r[k + 0], xr[k + 0], a0);
      a1 = fmaf(w1r[k + 1], xr[k + 1], a1);
      a2 = fmaf(w1r[k + 2], xr[k + 2], a2);
      a3 = fmaf(w1r[k + 3], xr[k + 3], a3);
    }
    hpart[((size_t)ks * 512 + (b0 + bb)) * 128 + j] = (a0 + a1) + (a2 + a3);
  }
}

// ---------------- param_net stage 2: reduce partials + bias + relu ---------
__global__ __launch_bounds__(256) void k_paramnet2(
    const float* __restrict__ hpart, const float* __restrict__ b1,
    float* __restrict__ h) {
  const int idx = blockIdx.x * 256 + threadIdx.x;
  float s = b1[idx & 127];
#pragma unroll
  for (int ks = 0; ks < 32; ++ks) s += hpart[(size_t)ks * 65536 + idx];
  h[idx] = fmaxf(s, 0.f);
}

// ---------------- params = h @ W2 + b2 -> sigmoids -> state + stat partials
__global__ __launch_bounds__(256) void k_params_state(
    const float* __restrict__ h, const float* __restrict__ W2,
    const float* __restrict__ b2, const float* __restrict__ X,
    float* __restrict__ betaW, float* __restrict__ sigmaW,
    float* __restrict__ gammaW, float* __restrict__ S0W,
    float* __restrict__ E0W, float* __restrict__ I0W,
    float* __restrict__ stats) {
  const int b0 = blockIdx.x * 2;
  const int t = threadIdx.x;
  const float* h0 = h + (size_t)b0 * 128;
  const float* h1 = h0 + 128;
  float a00 = b2[t], a01 = b2[256 + t], a02 = b2[512 + t], a03 = b2[768 + t];
  float a10 = a00, a11 = a01, a12 = a02, a13 = a03;
#pragma unroll 2
  for (int k = 0; k < 128; ++k) {
    const float* wr = W2 + (size_t)k * 1024;
    const float w0 = wr[t], w1 = wr[256 + t], w2 = wr[512 + t], w3 = wr[768 + t];
    const float hv0 = h0[k], hv1 = h1[k];
    a00 = fmaf(hv0, w0, a00); a01 = fmaf(hv0, w1, a01);
    a02 = fmaf(hv0, w2, a02); a03 = fmaf(hv0, w3, a03);
    a10 = fmaf(hv1, w0, a10); a11 = fmaf(hv1, w1, a11);
    a12 = fmaf(hv1, w2, a12); a13 = fmaf(hv1, w3, a13);
  }
  float bsum = 0.f, ssum = 0.f, gsum = 0.f;
#pragma unroll
  for (int j = 0; j < 2; ++j) {
    const float p0 = j ? a10 : a00, p1 = j ? a11 : a01;
    const float p2 = j ? a12 : a02, p3 = j ? a13 : a03;
    const float beta = 3.f / (1.f + __expf(-p0));
    const float sig  = 1.f / (1.f + __expf(-p1));
    const float gam  = 1.f / (1.f + __expf(-p2));
    const float e0r  = 5.f / (1.f + __expf(-p3));
    const int base = (b0 + j) * 256 + t;
    const float I0 = fmaxf(X[(size_t)(b0 + j) * 4096 + 15 * 256 + t], 1e-6f);
    const float E0 = I0 * e0r;
    const float S0 = fmaxf(1.f - E0 - I0, 0.01f);
    betaW[base] = beta; sigmaW[base] = sig; gammaW[base] = gam;
    S0W[base] = S0; E0W[base] = E0; I0W[base] = I0;
    bsum += beta; ssum += sig; gsum += gam;
  }
  atomicAdd(stats + t, bsum);
  atomicAdd(stats + 256 + t, ssum);
  atomicAdd(stats + 512 + t, gsum);
}

// ---------------- mobility stage 1: hm = relu(cnn @ M1 + mb1) as f16 -------
__global__ __launch_bounds__(128) void k_mobility1(
    const float* __restrict__ cnn, const float* __restrict__ M1,
    const float* __restrict__ mb1, _Float16* __restrict__ hmf) {
  const int b = blockIdx.x, j = threadIdx.x;
  const float* cr = cnn + b * 64;
  float a = mb1[j];
#pragma unroll
  for (int k = 0; k < 64; ++k) a = fmaf(cr[k], M1[k * 128 + j], a);
  hmf[b * 128 + j] = (_Float16)fmaxf(a, 0.f);
}

// ---------------- transpose M2 -> M2T[n][m][k] f16, LDS-tiled --------------
// Old version gathered 256B chunks at 256KB stride (DRAM page thrash on a
// 134MB input). Now: per block (one n), 128 fully-contiguous 1KB coalesced
// row reads -> LDS [k][m] (2-way bank = free), column gather, 16B-contig
// global writes.
__global__ __launch_bounds__(256) void k_cvtM2(
    const float* __restrict__ M2, _Float16* __restrict__ M2T) {
  const int n = blockIdx.x, t = threadIdx.x;
  __shared__ _Float16 sm[128 * 256];  // 64 KB
  const float* src = M2 + (size_t)n * 256 + t;
#pragma unroll 8
  for (int k = 0; k < 128; ++k)
    sm[k * 256 + t] = (_Float16)src[(size_t)k * 65536];
  __syncthreads();
  half2_t col[64];
#pragma unroll 16
  for (int k2 = 0; k2 < 64; ++k2)
    col[k2] = half2_t{sm[(2 * k2) * 256 + t], sm[(2 * k2 + 1) * 256 + t]};
  uint4* dst = (uint4*)(M2T + ((size_t)n * 256 + t) * 128);
  const uint4* s4 = (const uint4*)col;
#pragma unroll
  for (int i = 0; i < 16; ++i) dst[i] = s4[i];
}

// ---------------- mobility stage 2: MFMA GEMM + in-register softmax --------
__global__ __launch_bounds__(512, 2) void k_mobility2(
    const _Float16* __restrict__ hmf, const _Float16* __restrict__ M2T,
    const float* __restrict__ mb2, _Float16* __restrict__ PiF,
    float* __restrict__ pimpart) {
  const int n = blockIdx.x;
  const int pass = blockIdx.y;
  const int tid = threadIdx.x;
  const int wave = tid >> 6;
  const int lane = tid & 63;
  const int q = lane >> 4;
  const int c = lane & 15;

  __shared__ _Float16 sm[8][16 * 256];  // 64 KB, wave-private slots

  const _Float16* Bbase = M2T + (size_t)n * 32768 + (size_t)c * 128 + q * 8;
  const float* mbp = mb2 + n * 256 + c;

  const int bt0 = wave * 4 + pass * 2;
  f32x4 C0[16], C1[16];
#pragma unroll
  for (int nb = 0; nb < 16; ++nb) {
    const float mbv = mbp[nb * 16];
    C0[nb] = f32x4{mbv, mbv, mbv, mbv};
    C1[nb] = C0[nb];
  }
  const _Float16* A0 = hmf + (size_t)(bt0 * 16 + c) * 128 + q * 8;
  const _Float16* A1 = A0 + 16 * 128;
#pragma unroll
  for (int ks = 0; ks < 4; ++ks) {
    const f16x8 Af0 = *(const f16x8*)(A0 + ks * 32);
    const f16x8 Af1 = *(const f16x8*)(A1 + ks * 32);
#pragma unroll
    for (int nb = 0; nb < 16; ++nb) {
      const f16x8 Bf = *(const f16x8*)(Bbase + nb * 2048 + ks * 32);
      C0[nb] = __builtin_amdgcn_mfma_f32_16x16x32_f16(Af0, Bf, C0[nb], 0, 0, 0);
      C1[nb] = __builtin_amdgcn_mfma_f32_16x16x32_f16(Af1, Bf, C1[nb], 0, 0, 0);
    }
  }

  float colsum[16];
#pragma unroll
  for (int nb = 0; nb < 16; ++nb) colsum[nb] = 0.f;

#pragma unroll
  for (int half = 0; half < 2; ++half) {
    f32x4* C = half ? C1 : C0;
    const int bt = bt0 + half;
    float mx[4], sum[4];
#pragma unroll
    for (int r = 0; r < 4; ++r) mx[r] = C[0][r];
#pragma unroll
    for (int nb = 1; nb < 16; ++nb)
#pragma unroll
      for (int r = 0; r < 4; ++r) mx[r] = fmaxf(mx[r], C[nb][r]);
#pragma unroll
    for (int r = 0; r < 4; ++r) {
      mx[r] = fmaxf(mx[r], __shfl_xor(mx[r], 1, 16));
      mx[r] = fmaxf(mx[r], __shfl_xor(mx[r], 2, 16));
      mx[r] = fmaxf(mx[r], __shfl_xor(mx[r], 4, 16));
      mx[r] = fmaxf(mx[r], __shfl_xor(mx[r], 8, 16));
      sum[r] = 0.f;
    }
#pragma unroll
    for (int nb = 0; nb < 16; ++nb)
#pragma unroll
      for (int r = 0; r < 4; ++r) {
        const float e = __expf(C[nb][r] - mx[r]);
        C[nb][r] = e;
        sum[r] += e;
      }
#pragma unroll
    for (int r = 0; r < 4; ++r) {
      sum[r] += __shfl_xor(sum[r], 1, 16);
      sum[r] += __shfl_xor(sum[r], 2, 16);
      sum[r] += __shfl_xor(sum[r], 4, 16);
      sum[r] += __shfl_xor(sum[r], 8, 16);
      sum[r] = 1.f / sum[r];
    }
    _Float16* slot = sm[wave];
#pragma unroll
    for (int nb = 0; nb < 16; ++nb) {
#pragma unroll
      for (int r = 0; r < 4; ++r) {
        const float v = C[nb][r] * sum[r];
        colsum[nb] += v;
        slot[(q * 4 + r) * 256 + nb * 16 + c] = (_Float16)v;
      }
    }
    const int l2 = lane & 31, rh = lane >> 5;
    _Float16* Pg = PiF + ((size_t)(bt * 16) * 256 + n) * 256;
#pragma unroll
    for (int i = 0; i < 8; ++i) {
      const int row = i * 2 + rh;
      const uint4 v = *(const uint4*)(slot + row * 256 + l2 * 8);
      *(uint4*)(Pg + (size_t)row * 65536 + l2 * 8) = v;
    }
  }
#pragma unroll
  for (int nb = 0; nb < 16; ++nb) {
    colsum[nb] += __shfl_xor(colsum[nb], 16);
    colsum[nb] += __shfl_xor(colsum[nb], 32);
  }
  if (lane < 16) {
    float* pp = pimpart + n * 256 + lane;
#pragma unroll
    for (int nb = 0; nb < 16; ++nb) atomicAdd(pp + nb * 16, colsum[nb]);
  }
}

// ---------------- means: scale stats + Pi-mean partials --------------------
__global__ __launch_bounds__(256) void k_finalize(
    const float* __restrict__ stats, const float* __restrict__ pimpart,
    float* __restrict__ out) {
  const int idx = blockIdx.x * 256 + threadIdx.x;
  const float inv = 1.f / 512.f;
  if (idx < 768) {
    out[3145728 + idx] = stats[idx] * inv;
  } else {
    const int pm = idx - 768;
    out[3146496 + pm] = pimpart[pm] * inv;
  }
}

// ---------------- SEIR RK4 simulation (MFMA force matvec) ------------------
// Thread (wave w, quad q, lane c) holds Pi B-fragments for mtiles 4w..4w+3:
// Bf[i][t][j] = Pi[n = t*32+q*8+j][m = (4w+i)*16+c]  (128 VGPRs).
// Per grads: 1 ds_write_b16 (own I), barrier, 8 broadcast ds_read_b128
// A-frags (all A rows = I vector), 32 mfma_16x16x32_f16, force = C col c
// (rows identical). DS 9 insts/wave/stage vs round-5's 17 + 64 readlanes;
// the 65536-MAC matvec moves to the idle MFMA pipe.
__global__ __launch_bounds__(256, 2) void k_sim(
    const _Float16* __restrict__ PiF, const float* __restrict__ betaW,
    const float* __restrict__ sigmaW, const float* __restrict__ gammaW,
    const float* __restrict__ S0W, const float* __restrict__ E0W,
    const float* __restrict__ I0W, float* __restrict__ out) {
  const int b = blockIdx.x;
  const int tid = threadIdx.x;
  const int w = tid >> 6, lane = tid & 63;
  const int q = lane >> 4, c = lane & 15;
  const int mown = (4 * w + q) * 16 + c;

  __shared__ __align__(16) _Float16 Ib[2][256];

  f16x8 Bf[4][8];
  {
    const _Float16* P = PiF + (size_t)b * 65536 + (size_t)(q * 8) * 256 + c;
#pragma unroll
    for (int i = 0; i < 4; ++i) {
#pragma unroll
      for (int t = 0; t < 8; ++t) {
        const _Float16* src = P + (size_t)(t * 32) * 256 + (4 * w + i) * 16;
        f16x8 v;
#pragma unroll
        for (int j = 0; j < 8; ++j) v[j] = src[(size_t)j * 256];
        Bf[i][t] = v;
      }
    }
  }

  const int base = b * 256 + mown;
  const float bet = betaW[base], sig = sigmaW[base], gam = gammaW[base];
  float S = S0W[base], E = E0W[base], I = I0W[base];

  int p = 0;
  auto grads = [&](float Ss, float Es, float Is, float& dS, float& dE, float& dI) {
    Ib[p][mown] = (_Float16)Is;
    __syncthreads();
    const f16x8* ia = (const f16x8*)Ib[p];
    p ^= 1;
    f32x4 C[4];
#pragma unroll
    for (int i = 0; i < 4; ++i) C[i] = f32x4{0.f, 0.f, 0.f, 0.f};
#pragma unroll
    for (int t = 0; t < 8; ++t) {
      const f16x8 A = ia[t * 4 + q];  // element offset t*32 + q*8
#pragma unroll
      for (int i = 0; i < 4; ++i)
        C[i] = __builtin_amdgcn_mfma_f32_16x16x32_f16(A, Bf[i][t], C[i], 0, 0, 0);
    }
    // force for m = (4w+q)*16+c lives in C[q] (all rows identical)
    const float force = (q & 2) ? ((q & 1) ? C[3][0] : C[2][0])
                                : ((q & 1) ? C[1][0] : C[0][0]);
    const float ninf = bet * Ss * force;
    const float sE = sig * Es;
    dS = -ninf;
    dE = ninf - sE;
    dI = sE - gam * Is;
  };

  float* outI = out + (size_t)b * (12 * 256) + mown;
  float* outE = outI + 1572864;
  const float c6 = 0.25f / 6.f;

  for (int wk = 0; wk < 12; ++wk) {
    for (int st = 0; st < 4; ++st) {
      float d1S, d1E, d1I, d2S, d2E, d2I, d3S, d3E, d3I, d4S, d4E, d4I;
      grads(S, E, I, d1S, d1E, d1I);
      grads(S + 0.125f * d1S, E + 0.125f * d1E, I + 0.125f * d1I, d2S, d2E, d2I);
      grads(S + 0.125f * d2S, E + 0.125f * d2E, I + 0.125f * d2I, d3S, d3E, d3I);
      grads(S + 0.25f * d3S, E + 0.25f * d3E, I + 0.25f * d3I, d4S, d4E, d4I);
      S = fminf(fmaxf(S + c6 * (d1S + 2.f * d2S + 2.f * d3S + d4S), 0.f), 1.f);
      E = fminf(fmaxf(E + c6 * (d1E + 2.f * d2E + 2.f * d3E + d4E), 0.f), 1.f);
      I = fminf(fmaxf(I + c6 * (d1I + 2.f * d2I + 2.f * d3I + d4I), 0.f), 1.f);
    }
    outI[wk * 256] = I;
    outE[wk * 256] = E;
  }
}

// ---------------- launch ---------------------------------------------------
extern "C" void kernel_launch(void* const* d_in, const int* in_sizes, int n_in,
                              void* d_out, int out_size, void* d_ws, size_t ws_size,
                              hipStream_t stream) {
  const float* x_hist = (const float*)d_in[0];
  const float* cnn    = (const float*)d_in[1];
  const float* W1     = (const float*)d_in[2];
  const float* b1     = (const float*)d_in[3];
  const float* W2     = (const float*)d_in[4];
  const float* b2     = (const float*)d_in[5];
  const float* M1     = (const float*)d_in[6];
  const float* mb1    = (const float*)d_in[7];
  const float* M2     = (const float*)d_in[8];
  const float* mb2    = (const float*)d_in[9];
  float* out = (float*)d_out;

  char* w = (char*)d_ws;
  _Float16* M2T     = (_Float16*)(w + 0);         // 16,777,216
  _Float16* hmf     = (_Float16*)(w + 16777216);  //    131,072
  float*    betaW   = (float*)(w + 16908288);     //    524,288 each
  float*    sigmaW  = (float*)(w + 17432576);
  float*    gammaW  = (float*)(w + 17956864);
  float*    S0W     = (float*)(w + 18481152);
  float*    E0W     = (float*)(w + 19005440);
  float*    I0W     = (float*)(w + 19529728);
  float*    pimpart = (float*)(w + 20054016);     //    262,144
  float*    stats   = (float*)(w + 20316160);     //      4,096 (768 used)
  _Float16* PiF     = (_Float16*)(w + 20320256);  // 67,108,864 (end 87.4MB)
  // hpart/h alias the PiF region (dead before k_mobility2 writes PiF)
  float*    hpart   = (float*)(w + 20320256);     //  8,388,608
  float*    h       = (float*)(w + 28708864);     //    262,144

  hipMemsetAsync(pimpart, 0, 266240, stream);  // pimpart + stats
  k_paramnet1<<<dim3(32, 16), 128, 0, stream>>>(x_hist, W1, hpart);
  k_paramnet2<<<256, 256, 0, stream>>>(hpart, b1, h);
  k_params_state<<<256, 256, 0, stream>>>(h, W2, b2, x_hist, betaW, sigmaW,
                                          gammaW, S0W, E0W, I0W, stats);
  k_mobility1<<<512, 128, 0, stream>>>(cnn, M1, mb1, hmf);
  k_cvtM2<<<256, 256, 0, stream>>>(M2, M2T);
  k_mobility2<<<dim3(256, 2), 512, 0, stream>>>(hmf, M2T, mb2, PiF, pimpart);
  k_finalize<<<259, 256, 0, stream>>>(stats, pimpart, out);
  k_sim<<<512, 256, 0, stream>>>(PiF, betaW, sigmaW, gammaW, S0W, E0W, I0W, out);
}